// Round 6
// baseline (206.776 us; speedup 1.0000x reference)
//
#include <hip/hip_runtime.h>
#include <hip/hip_bf16.h>
#include <math.h>

// Problem constants (from reference setup_inputs)
#define BB 2
#define CC 32
#define HH 128
#define WW 160
#define DD 32
#define NN 4
#define HW (HH * WW)        // 20480
#define GG 8

typedef float v2f __attribute__((ext_vector_type(2)));

// ---------------------------------------------------------------------------
// Device helper: per-(b,src) projection matrices (FP64 Gauss-Jordan).
// Executed by threads 0..7 of one block of the prep kernel.
// ---------------------------------------------------------------------------
__device__ void compute_mats(int t, const float* __restrict__ proj,
                             float* __restrict__ mats) {
    int b = t >> 2, n = t & 3;
    const float* Er = proj + ((size_t)(b * (NN + 1) + 0) * 2 + 0) * 16;
    const float* Kr = proj + ((size_t)(b * (NN + 1) + 0) * 2 + 1) * 16;
    const float* Es = proj + ((size_t)(b * (NN + 1) + n + 1) * 2 + 0) * 16;
    const float* Ks = proj + ((size_t)(b * (NN + 1) + n + 1) * 2 + 1) * 16;

    double A[4][4], Bm[4][4];
    for (int r = 0; r < 4; r++)
        for (int c = 0; c < 4; c++) {
            if (r < 3) {
                A[r][c]  = (double)Kr[r*4+0]*Er[0*4+c] + (double)Kr[r*4+1]*Er[1*4+c] + (double)Kr[r*4+2]*Er[2*4+c];
                Bm[r][c] = (double)Ks[r*4+0]*Es[0*4+c] + (double)Ks[r*4+1]*Es[1*4+c] + (double)Ks[r*4+2]*Es[2*4+c];
            } else {
                A[r][c]  = (double)Er[12 + c];
                Bm[r][c] = (double)Es[12 + c];
            }
        }
    double M[4][8];
    for (int i = 0; i < 4; i++)
        for (int j = 0; j < 4; j++) { M[i][j] = A[i][j]; M[i][4+j] = (i == j) ? 1.0 : 0.0; }
    for (int col = 0; col < 4; col++) {
        int piv = col;
        for (int r = col + 1; r < 4; r++)
            if (fabs(M[r][col]) > fabs(M[piv][col])) piv = r;
        if (piv != col)
            for (int j = 0; j < 8; j++) { double tmp = M[col][j]; M[col][j] = M[piv][j]; M[piv][j] = tmp; }
        double pv = M[col][col];
        for (int j = 0; j < 8; j++) M[col][j] /= pv;
        for (int r = 0; r < 4; r++) {
            if (r == col) continue;
            double f = M[r][col];
            for (int j = 0; j < 8; j++) M[r][j] -= f * M[col][j];
        }
    }
    float* o = mats + t * 12;
    for (int i = 0; i < 3; i++) {
        double p0 = 0, p1 = 0, p2 = 0, p3 = 0;
        for (int k = 0; k < 4; k++) {
            p0 += Bm[i][k] * M[k][4+0];
            p1 += Bm[i][k] * M[k][4+1];
            p2 += Bm[i][k] * M[k][4+2];
            p3 += Bm[i][k] * M[k][4+3];
        }
        o[i*3+0] = (float)p0; o[i*3+1] = (float)p1; o[i*3+2] = (float)p2;
        o[9 + i] = (float)p3;
    }
}

// ---------------------------------------------------------------------------
// Kernel 1: merged transpose [32][HW] -> [HW][32]; slabs 0-7 = src, 8-9 = ref.
// Block (0,0) additionally computes the 8 projection matrices (tid<8).
// ---------------------------------------------------------------------------
__global__ __launch_bounds__(256) void prep_transpose(const float* __restrict__ src,
                                                      const float* __restrict__ ref,
                                                      const float* __restrict__ proj,
                                                      float* __restrict__ srcT,
                                                      float* __restrict__ refT,
                                                      float* __restrict__ mats) {
    if (blockIdx.x == 0 && blockIdx.y == 0 && threadIdx.x < 8)
        compute_mats(threadIdx.x, proj, mats);

    __shared__ float t[32][33];
    int slab = blockIdx.y;
    const float* ip;
    float* op;
    if (slab < 8) { ip = src + (size_t)slab * 32 * HW; op = srcT + (size_t)slab * 32 * HW; }
    else          { ip = ref + (size_t)(slab - 8) * 32 * HW; op = refT + (size_t)(slab - 8) * 32 * HW; }
    int hw0 = blockIdx.x * 32;
    int tx = threadIdx.x & 31, ty = threadIdx.x >> 5;
#pragma unroll
    for (int i = 0; i < 4; i++) {
        int c = ty + i * 8;
        t[c][tx] = ip[(size_t)c * HW + hw0 + tx];
    }
    __syncthreads();
#pragma unroll
    for (int i = 0; i < 4; i++) {
        int hl = ty + i * 8;
        op[(size_t)(hw0 + hl) * 32 + tx] = t[tx][hl];
    }
}

// ---------------------------------------------------------------------------
// Kernel 2: main fused kernel. Block = 256 threads = one ref pixel.
// Thread (d,g): d = tid>>3 (depth 0..31), g = tid&7 (channel group).
// Phase 0: mats staged in LDS; one homography per lane (n0 = tid&3).
// Phase 1: hoisted shuffles + 2-deep pipelined gathers; packed-fp32 blend+dot.
// Stats  : wave 0 alone computes cw[n][d] + cwsum[d] tables (softmax over D).
// Phase 2: per-thread cf = 4 LDS reads + 4 FMA; logit2 -> sE.
// Final  : wave 0 alone does final softmax, attn writes, argmax depth write.
// ---------------------------------------------------------------------------
__global__ __launch_bounds__(256, 6) void main_kernel(
    const float* __restrict__ srcT,   // (N*B, HW, 32) channels-last
    const float* __restrict__ refT,   // (B,   HW, 32) channels-last
    const float* __restrict__ depth,  // (B, D, H, W) original layout
    const float* __restrict__ mats,   // (B*N, 12) rot row-major + trans
    const float* __restrict__ regw,   // (8,)
    const float* __restrict__ regb,   // (1,)
    float* __restrict__ out)          // [B*HW depth][B*D*HW attn]
{
    int tid = threadIdx.x;
    int g  = tid & 7;
    int d  = tid >> 3;      // 0..31

    int p   = blockIdx.x;   // global pixel 0..B*HW-1
    int b   = p / HW;
    int rem = p - b * HW;
    int y   = rem / WW;
    int x   = rem - y * WW;
    float fx = (float)x, fy = (float)y;

    __shared__ float sM[48];        // this block's 4 projection matrices
    __shared__ float sL[NN][DD];    // per-source logits over depth
    __shared__ float sCW[NN][DD];   // per-source softmax weights (w/ 1/sqrt(C))
    __shared__ float sCWS[DD];      // sum over sources of cw + 1e-8
    __shared__ float sE[DD];        // final logits over depth
    __shared__ float sDep[DD];      // depth hypothesis per d

    if (tid < 48) sM[tid] = mats[(size_t)b * 48 + tid];

    // this thread's group of the ref feature (one float4)
    float4 R = *(const float4*)(refT + (size_t)p * 32 + g * 4);
    v2f Rlo = { R.x, R.y }, Rhi = { R.z, R.w };
    float dep = depth[((size_t)(b * DD + d) * HH + y) * WW + x];
    float rwg = regw[g];
    float rb  = regb[0];
    if (g == 0) sDep[d] = dep;
    __syncthreads();   // barrier 0: sM ready

    // ---- Phase 0: one homography per lane, for source n0 = tid&3 at depth d
    float W00, W10, W01, W11;
    int   I00, I10, I01, I11;
    {
        int n0 = tid & 3;
        float4 m0 = *(const float4*)(sM + n0 * 12);      // 48B-aligned
        float4 m1 = *(const float4*)(sM + n0 * 12 + 4);
        float4 m2 = *(const float4*)(sM + n0 * 12 + 8);
        float ax = m0.x * fx + m0.y * fy + m0.z;
        float ay = m0.w * fx + m1.x * fy + m1.y;
        float az = m1.z * fx + m1.w * fy + m2.x;
        float px = ax * dep + m2.y;
        float py = ay * dep + m2.z;
        float pz = az * dep + m2.w;
        float z  = (pz == 0.f) ? 1e-9f : pz;
        float rz = __builtin_amdgcn_rcpf(z);
        float gx = px * rz, gy = py * rz;

        float x0f = floorf(gx), y0f = floorf(gy);
        float wx = gx - x0f, wy = gy - y0f;
        bool vx0 = (x0f >= 0.f)  && (x0f <= (float)(WW - 1));
        bool vx1 = (x0f >= -1.f) && (x0f <= (float)(WW - 2));
        bool vy0 = (y0f >= 0.f)  && (y0f <= (float)(HH - 1));
        bool vy1 = (y0f >= -1.f) && (y0f <= (float)(HH - 2));
        W00 = (vx0 && vy0) ? (1.f - wx) * (1.f - wy) : 0.f;
        W10 = (vx1 && vy0) ? wx * (1.f - wy)         : 0.f;
        W01 = (vx0 && vy1) ? (1.f - wx) * wy         : 0.f;
        W11 = (vx1 && vy1) ? wx * wy                 : 0.f;

        int xi0 = (int)fminf(fmaxf(x0f,       0.f), (float)(WW - 1));
        int xi1 = (int)fminf(fmaxf(x0f + 1.f, 0.f), (float)(WW - 1));
        int yi0 = (int)fminf(fmaxf(y0f,       0.f), (float)(HH - 1));
        int yi1 = (int)fminf(fmaxf(y0f + 1.f, 0.f), (float)(HH - 1));
        I00 = yi0 * WW + xi0;
        I10 = yi0 * WW + xi1;
        I01 = yi1 * WW + xi0;
        I11 = yi1 * WW + xi1;
    }

    // ---- Hoist all shuffled weights/indices (lane (tid&56)|n holds (n, my d))
    float4 Wn[NN];
    int4   In[NN];
#pragma unroll
    for (int n = 0; n < NN; n++) {
        int src_lane = (tid & 56) | n;
        Wn[n].x = __shfl(W00, src_lane);
        Wn[n].y = __shfl(W10, src_lane);
        Wn[n].z = __shfl(W01, src_lane);
        Wn[n].w = __shfl(W11, src_lane);
        In[n].x = __shfl(I00, src_lane);
        In[n].y = __shfl(I10, src_lane);
        In[n].z = __shfl(I01, src_lane);
        In[n].w = __shfl(I11, src_lane);
    }

    float cor[NN];
    float4 ta[2], tb[2], tc[2], te[2];

    auto issue = [&](int n, int s) {
        const float4* S4 = (const float4*)(srcT + (size_t)(n * BB + b) * (32 * HW));
        ta[s] = S4[(size_t)In[n].x * 8 + g];
        tb[s] = S4[(size_t)In[n].y * 8 + g];
        tc[s] = S4[(size_t)In[n].z * 8 + g];
        te[s] = S4[(size_t)In[n].w * 8 + g];
    };
    auto consume = [&](int n, int s) {
        float4 a = ta[s], bq = tb[s], c = tc[s], e = te[s];
        v2f alo = { a.x, a.y },  ahi = { a.z, a.w };
        v2f blo = { bq.x, bq.y }, bhi = { bq.z, bq.w };
        v2f clo = { c.x, c.y },  chi = { c.z, c.w };
        v2f elo = { e.x, e.y },  ehi = { e.z, e.w };
        float w00 = Wn[n].x, w10 = Wn[n].y, w01 = Wn[n].z, w11 = Wn[n].w;
        v2f wlo = w00 * alo + w10 * blo + w01 * clo + w11 * elo;
        v2f whi = w00 * ahi + w10 * bhi + w01 * chi + w11 * ehi;
        v2f pr  = wlo * Rlo + whi * Rhi;
        float cr = pr.x + pr.y;
        cor[n] = cr;
        // sum over the 8 channel-groups (octet butterfly; lane-invariant)
        float ls = cr;
        ls += __shfl_xor(ls, 1);
        ls += __shfl_xor(ls, 2);
        ls += __shfl_xor(ls, 4);
        if (g == 0) sL[n][d] = ls * 0.125f;  // mean over C//G=4 then /attn_temp
    };

    // ---- Phase 1: 2-deep pipelined gathers (8 loads in flight)
    issue(0, 0); issue(1, 1);
    consume(0, 0); issue(2, 0);
    consume(1, 1); issue(3, 1);
    consume(2, 0); consume(3, 1);
    __syncthreads();   // barrier 1: sL fully populated

    // ---- Stats: wave 0 computes cw[n][d] and cwsum[d] for all n,d
    if (tid < 64) {
        int n  = tid >> 4;       // 0..3
        int dh = tid & 15;       // 0..15; covers d=dh and d=dh+16
        float l0 = sL[n][dh];
        float l1 = sL[n][dh + 16];
        float m = fmaxf(l0, l1);
        m = fmaxf(m, __shfl_xor(m, 1));
        m = fmaxf(m, __shfl_xor(m, 2));
        m = fmaxf(m, __shfl_xor(m, 4));
        m = fmaxf(m, __shfl_xor(m, 8));
        float e0 = __expf(l0 - m), e1 = __expf(l1 - m);
        float s = e0 + e1;
        s += __shfl_xor(s, 1);
        s += __shfl_xor(s, 2);
        s += __shfl_xor(s, 4);
        s += __shfl_xor(s, 8);
        float f = 0.17677669529663687f / s;   // fold 1/sqrt(C=32)
        float c0 = e0 * f, c1 = e1 * f;
        sCW[n][dh]      = c0;
        sCW[n][dh + 16] = c1;
        // cross-source sum per depth (lanes with same dh across the 4 n-groups)
        float t0 = c0, t1 = c1;
        t0 += __shfl_xor(t0, 16); t0 += __shfl_xor(t0, 32);
        t1 += __shfl_xor(t1, 16); t1 += __shfl_xor(t1, 32);
        if (n == 0) {
            sCWS[dh]      = t0 + 1e-8f;
            sCWS[dh + 16] = t1 + 1e-8f;
        }
    }
    __syncthreads();   // barrier 2: sCW/sCWS ready

    // ---- Phase 2: per-thread weighted accumulation + reg projection
    float cf = 0.f;
#pragma unroll
    for (int n = 0; n < NN; n++) cf += sCW[n][d] * cor[n];
    cf *= 0.25f;                         // fold mean(C//G=4) factor
    float v = cf * rwg;
    v += __shfl_xor(v, 1);
    v += __shfl_xor(v, 2);
    v += __shfl_xor(v, 4);
    float logit2 = v * __builtin_amdgcn_rcpf(sCWS[d]) + rb;  // same across octet
    if (g == 0) sE[d] = logit2;
    __syncthreads();   // barrier 3: sE fully populated

    // ---- Final: wave 0 alone — softmax over D, attn writes, argmax depth
    if (tid < 64) {
        int dl = tid & 31;               // both wave halves compute identically
        float q = sE[dl];
        float m2 = q;
        m2 = fmaxf(m2, __shfl_xor(m2, 1));
        m2 = fmaxf(m2, __shfl_xor(m2, 2));
        m2 = fmaxf(m2, __shfl_xor(m2, 4));
        m2 = fmaxf(m2, __shfl_xor(m2, 8));
        m2 = fmaxf(m2, __shfl_xor(m2, 16));
        float e2 = __expf(q - m2);
        float t2 = e2;
        t2 += __shfl_xor(t2, 1);
        t2 += __shfl_xor(t2, 2);
        t2 += __shfl_xor(t2, 4);
        t2 += __shfl_xor(t2, 8);
        t2 += __shfl_xor(t2, 16);
        float aw = e2 / t2;
        if (tid < 32)
            out[(size_t)BB * HW + (size_t)(b * DD + dl) * HW + rem] = aw;

        // argmax over D (first-max semantics), within each 32-lane half
        float bv = q; int bi = dl;
#pragma unroll
        for (int s = 1; s <= 16; s <<= 1) {
            float ov = __shfl_xor(bv, s);
            int   oi = __shfl_xor(bi, s);
            if (ov > bv || (ov == bv && oi < bi)) { bv = ov; bi = oi; }
        }
        if (tid < 32 && dl == bi) out[p] = sDep[bi];
    }
}

// ---------------------------------------------------------------------------
extern "C" void kernel_launch(void* const* d_in, const int* in_sizes, int n_in,
                              void* d_out, int out_size, void* d_ws, size_t ws_size,
                              hipStream_t stream) {
    const float* ref   = (const float*)d_in[0];  // (B,C,H,W)
    const float* src   = (const float*)d_in[1];  // (N,B,C,H,W)
    const float* proj  = (const float*)d_in[2];  // (B,N+1,2,4,4)
    const float* depth = (const float*)d_in[3];  // (B,D,H,W)
    const float* regw  = (const float*)d_in[4];  // (8,)
    const float* regb  = (const float*)d_in[5];  // (1,)
    float* out = (float*)d_out;

    float* ws   = (float*)d_ws;
    float* mats = ws;                                 // 96 floats (pad to 256)
    float* srcT = ws + 256;                           // N*B*HW*32 = 5,242,880
    float* refT = srcT + (size_t)NN * BB * HW * 32;   // B*HW*32 = 1,310,720

    prep_transpose<<<dim3(HW / 32, 10), 256, 0, stream>>>(src, ref, proj,
                                                          srcT, refT, mats);
    main_kernel<<<BB * HW, 256, 0, stream>>>(srcT, refT, depth, mats,
                                             regw, regb, out);
}

// Round 7
// 197.633 us; speedup vs baseline: 1.0463x; 1.0463x over previous
//
#include <hip/hip_runtime.h>
#include <hip/hip_bf16.h>
#include <math.h>

// Problem constants (from reference setup_inputs)
#define BB 2
#define CC 32
#define HH 128
#define WW 160
#define DD 32
#define NN 4
#define HW (HH * WW)        // 20480
#define GG 8

typedef float v2f __attribute__((ext_vector_type(2)));

// ---------------------------------------------------------------------------
// Device helper: per-(b,src) projection matrices (FP64 Gauss-Jordan).
// Executed by threads 0..7 of one block of the prep kernel.
// ---------------------------------------------------------------------------
__device__ void compute_mats(int t, const float* __restrict__ proj,
                             float* __restrict__ mats) {
    int b = t >> 2, n = t & 3;
    const float* Er = proj + ((size_t)(b * (NN + 1) + 0) * 2 + 0) * 16;
    const float* Kr = proj + ((size_t)(b * (NN + 1) + 0) * 2 + 1) * 16;
    const float* Es = proj + ((size_t)(b * (NN + 1) + n + 1) * 2 + 0) * 16;
    const float* Ks = proj + ((size_t)(b * (NN + 1) + n + 1) * 2 + 1) * 16;

    double A[4][4], Bm[4][4];
    for (int r = 0; r < 4; r++)
        for (int c = 0; c < 4; c++) {
            if (r < 3) {
                A[r][c]  = (double)Kr[r*4+0]*Er[0*4+c] + (double)Kr[r*4+1]*Er[1*4+c] + (double)Kr[r*4+2]*Er[2*4+c];
                Bm[r][c] = (double)Ks[r*4+0]*Es[0*4+c] + (double)Ks[r*4+1]*Es[1*4+c] + (double)Ks[r*4+2]*Es[2*4+c];
            } else {
                A[r][c]  = (double)Er[12 + c];
                Bm[r][c] = (double)Es[12 + c];
            }
        }
    double M[4][8];
    for (int i = 0; i < 4; i++)
        for (int j = 0; j < 4; j++) { M[i][j] = A[i][j]; M[i][4+j] = (i == j) ? 1.0 : 0.0; }
    for (int col = 0; col < 4; col++) {
        int piv = col;
        for (int r = col + 1; r < 4; r++)
            if (fabs(M[r][col]) > fabs(M[piv][col])) piv = r;
        if (piv != col)
            for (int j = 0; j < 8; j++) { double tmp = M[col][j]; M[col][j] = M[piv][j]; M[piv][j] = tmp; }
        double pv = M[col][col];
        for (int j = 0; j < 8; j++) M[col][j] /= pv;
        for (int r = 0; r < 4; r++) {
            if (r == col) continue;
            double f = M[r][col];
            for (int j = 0; j < 8; j++) M[r][j] -= f * M[col][j];
        }
    }
    float* o = mats + t * 12;
    for (int i = 0; i < 3; i++) {
        double p0 = 0, p1 = 0, p2 = 0, p3 = 0;
        for (int k = 0; k < 4; k++) {
            p0 += Bm[i][k] * M[k][4+0];
            p1 += Bm[i][k] * M[k][4+1];
            p2 += Bm[i][k] * M[k][4+2];
            p3 += Bm[i][k] * M[k][4+3];
        }
        o[i*3+0] = (float)p0; o[i*3+1] = (float)p1; o[i*3+2] = (float)p2;
        o[9 + i] = (float)p3;
    }
}

// ---------------------------------------------------------------------------
// Kernel 1: merged transpose [32][HW] -> [HW][32]; slabs 0-7 = src, 8-9 = ref.
// Block (0,0) additionally computes the 8 projection matrices (tid<8).
// ---------------------------------------------------------------------------
__global__ __launch_bounds__(256) void prep_transpose(const float* __restrict__ src,
                                                      const float* __restrict__ ref,
                                                      const float* __restrict__ proj,
                                                      float* __restrict__ srcT,
                                                      float* __restrict__ refT,
                                                      float* __restrict__ mats) {
    if (blockIdx.x == 0 && blockIdx.y == 0 && threadIdx.x < 8)
        compute_mats(threadIdx.x, proj, mats);

    __shared__ float t[32][33];
    int slab = blockIdx.y;
    const float* ip;
    float* op;
    if (slab < 8) { ip = src + (size_t)slab * 32 * HW; op = srcT + (size_t)slab * 32 * HW; }
    else          { ip = ref + (size_t)(slab - 8) * 32 * HW; op = refT + (size_t)(slab - 8) * 32 * HW; }
    int hw0 = blockIdx.x * 32;
    int tx = threadIdx.x & 31, ty = threadIdx.x >> 5;
#pragma unroll
    for (int i = 0; i < 4; i++) {
        int c = ty + i * 8;
        t[c][tx] = ip[(size_t)c * HW + hw0 + tx];
    }
    __syncthreads();
#pragma unroll
    for (int i = 0; i < 4; i++) {
        int hl = ty + i * 8;
        op[(size_t)(hw0 + hl) * 32 + tx] = t[tx][hl];
    }
}

// ---------------------------------------------------------------------------
// Kernel 2: main fused kernel. Block = 256 threads = one ref pixel.
// Thread (d,g): d = tid>>3 (depth 0..31), g = tid&7 (channel group).
// Structure = round 5 (best occupancy/latency balance), with the two proven
// VALU cuts from round 6: v_rcp divides and packed-fp32 blend/dot.
// ---------------------------------------------------------------------------
__global__ __launch_bounds__(256) void main_kernel(
    const float* __restrict__ srcT,   // (N*B, HW, 32) channels-last
    const float* __restrict__ refT,   // (B,   HW, 32) channels-last
    const float* __restrict__ depth,  // (B, D, H, W) original layout
    const float* __restrict__ mats,   // (B*N, 12) rot row-major + trans
    const float* __restrict__ regw,   // (8,)
    const float* __restrict__ regb,   // (1,)
    float* __restrict__ out)          // [B*HW depth][B*D*HW attn]
{
    int tid = threadIdx.x;
    int g  = tid & 7;
    int d  = tid >> 3;      // 0..31

    int p   = blockIdx.x;   // global pixel 0..B*HW-1
    int b   = p / HW;
    int rem = p - b * HW;
    int y   = rem / WW;
    int x   = rem - y * WW;
    float fx = (float)x, fy = (float)y;

    // this thread's group of the ref feature (one float4)
    float4 R = *(const float4*)(refT + (size_t)p * 32 + g * 4);
    v2f Rlo = { R.x, R.y }, Rhi = { R.z, R.w };
    float dep = depth[((size_t)(b * DD + d) * HH + y) * WW + x];
    float rwg = regw[g];
    float rb  = regb[0];

    __shared__ float sL[NN][DD];    // per-source logits over depth
    __shared__ float sCW[NN][DD];   // per-source softmax weights (w/ 1/sqrt(C))
    __shared__ float sCWS[DD];      // sum over sources of cw + 1e-8
    __shared__ float sE[DD];        // final logits over depth
    __shared__ float sDep[DD];      // depth hypothesis per d

    if (g == 0) sDep[d] = dep;

    // ---- Phase 0: one homography per lane, for source n0 = tid&3 at depth d
    float W00, W10, W01, W11;
    int   I00, I10, I01, I11;
    {
        int n0 = tid & 3;
        const float* Mp = mats + (size_t)(b * NN + n0) * 12;
        float4 m0 = *(const float4*)(Mp);       // rows are 48B -> 16B aligned
        float4 m1 = *(const float4*)(Mp + 4);
        float4 m2 = *(const float4*)(Mp + 8);
        float ax = m0.x * fx + m0.y * fy + m0.z;
        float ay = m0.w * fx + m1.x * fy + m1.y;
        float az = m1.z * fx + m1.w * fy + m2.x;
        float px = ax * dep + m2.y;
        float py = ay * dep + m2.z;
        float pz = az * dep + m2.w;
        float z  = (pz == 0.f) ? 1e-9f : pz;
        float rz = __builtin_amdgcn_rcpf(z);
        float gx = px * rz, gy = py * rz;

        float x0f = floorf(gx), y0f = floorf(gy);
        float wx = gx - x0f, wy = gy - y0f;
        bool vx0 = (x0f >= 0.f)  && (x0f <= (float)(WW - 1));
        bool vx1 = (x0f >= -1.f) && (x0f <= (float)(WW - 2));
        bool vy0 = (y0f >= 0.f)  && (y0f <= (float)(HH - 1));
        bool vy1 = (y0f >= -1.f) && (y0f <= (float)(HH - 2));
        W00 = (vx0 && vy0) ? (1.f - wx) * (1.f - wy) : 0.f;
        W10 = (vx1 && vy0) ? wx * (1.f - wy)         : 0.f;
        W01 = (vx0 && vy1) ? (1.f - wx) * wy         : 0.f;
        W11 = (vx1 && vy1) ? wx * wy                 : 0.f;

        int xi0 = (int)fminf(fmaxf(x0f,       0.f), (float)(WW - 1));
        int xi1 = (int)fminf(fmaxf(x0f + 1.f, 0.f), (float)(WW - 1));
        int yi0 = (int)fminf(fmaxf(y0f,       0.f), (float)(HH - 1));
        int yi1 = (int)fminf(fmaxf(y0f + 1.f, 0.f), (float)(HH - 1));
        I00 = yi0 * WW + xi0;
        I10 = yi0 * WW + xi1;
        I01 = yi1 * WW + xi0;
        I11 = yi1 * WW + xi1;
    }

    float cor[NN];

    // ---- Phase 1: gathers + packed blend/dot + octet g-sum; no barriers
#pragma unroll
    for (int n = 0; n < NN; n++) {
        int src_lane = (tid & 56) | n;     // lane holding (n, my d)
        float w00 = __shfl(W00, src_lane);
        float w10 = __shfl(W10, src_lane);
        float w01 = __shfl(W01, src_lane);
        float w11 = __shfl(W11, src_lane);
        int   i00 = __shfl(I00, src_lane);
        int   i10 = __shfl(I10, src_lane);
        int   i01 = __shfl(I01, src_lane);
        int   i11 = __shfl(I11, src_lane);

        const float4* S4 = (const float4*)(srcT + (size_t)(n * BB + b) * (32 * HW));
        float4 a  = S4[(size_t)i00 * 8 + g];
        float4 bq = S4[(size_t)i10 * 8 + g];
        float4 c  = S4[(size_t)i01 * 8 + g];
        float4 e  = S4[(size_t)i11 * 8 + g];

        // packed-fp32 blend-then-dot
        v2f alo = { a.x, a.y },  ahi = { a.z, a.w };
        v2f blo = { bq.x, bq.y }, bhi = { bq.z, bq.w };
        v2f clo = { c.x, c.y },  chi = { c.z, c.w };
        v2f elo = { e.x, e.y },  ehi = { e.z, e.w };
        v2f wlo = w00 * alo + w10 * blo + w01 * clo + w11 * elo;
        v2f whi = w00 * ahi + w10 * bhi + w01 * chi + w11 * ehi;
        v2f pr  = wlo * Rlo + whi * Rhi;
        float cr = pr.x + pr.y;
        cor[n] = cr;

        // sum over the 8 channel-groups (octet butterfly; lane-invariant)
        float ls = cr;
        ls += __shfl_xor(ls, 1);
        ls += __shfl_xor(ls, 2);
        ls += __shfl_xor(ls, 4);
        if (g == 0) sL[n][d] = ls * 0.125f;  // mean over C//G=4 then /attn_temp
    }
    __syncthreads();   // barrier 1: sL fully populated

    // ---- Stats: wave 0 computes cw[n][d] and cwsum[d] for all n,d
    if (tid < 64) {
        int n  = tid >> 4;       // 0..3
        int dh = tid & 15;       // 0..15; covers d=dh and d=dh+16
        float l0 = sL[n][dh];
        float l1 = sL[n][dh + 16];
        float m = fmaxf(l0, l1);
        m = fmaxf(m, __shfl_xor(m, 1));
        m = fmaxf(m, __shfl_xor(m, 2));
        m = fmaxf(m, __shfl_xor(m, 4));
        m = fmaxf(m, __shfl_xor(m, 8));
        float e0 = __expf(l0 - m), e1 = __expf(l1 - m);
        float s = e0 + e1;
        s += __shfl_xor(s, 1);
        s += __shfl_xor(s, 2);
        s += __shfl_xor(s, 4);
        s += __shfl_xor(s, 8);
        float f = 0.17677669529663687f / s;   // fold 1/sqrt(C=32)
        float c0 = e0 * f, c1 = e1 * f;
        sCW[n][dh]      = c0;
        sCW[n][dh + 16] = c1;
        // cross-source sum per depth (lanes with same dh across the 4 n-groups)
        float t0 = c0, t1 = c1;
        t0 += __shfl_xor(t0, 16); t0 += __shfl_xor(t0, 32);
        t1 += __shfl_xor(t1, 16); t1 += __shfl_xor(t1, 32);
        if (n == 0) {
            sCWS[dh]      = t0 + 1e-8f;
            sCWS[dh + 16] = t1 + 1e-8f;
        }
    }
    __syncthreads();   // barrier 2: sCW/sCWS ready

    // ---- Phase 2: per-thread weighted accumulation + reg projection
    float cf = 0.f;
#pragma unroll
    for (int n = 0; n < NN; n++) cf += sCW[n][d] * cor[n];
    cf *= 0.25f;                         // fold mean(C//G=4) factor
    float v = cf * rwg;
    v += __shfl_xor(v, 1);
    v += __shfl_xor(v, 2);
    v += __shfl_xor(v, 4);
    float logit2 = v * __builtin_amdgcn_rcpf(sCWS[d]) + rb;  // same across octet
    if (g == 0) sE[d] = logit2;
    __syncthreads();   // barrier 3: sE fully populated

    // ---- Final: wave 0 alone — softmax over D, attn writes, argmax depth
    if (tid < 64) {
        int dl = tid & 31;               // both wave halves compute identically
        float q = sE[dl];
        float m2 = q;
        m2 = fmaxf(m2, __shfl_xor(m2, 1));
        m2 = fmaxf(m2, __shfl_xor(m2, 2));
        m2 = fmaxf(m2, __shfl_xor(m2, 4));
        m2 = fmaxf(m2, __shfl_xor(m2, 8));
        m2 = fmaxf(m2, __shfl_xor(m2, 16));
        float e2 = __expf(q - m2);
        float t2 = e2;
        t2 += __shfl_xor(t2, 1);
        t2 += __shfl_xor(t2, 2);
        t2 += __shfl_xor(t2, 4);
        t2 += __shfl_xor(t2, 8);
        t2 += __shfl_xor(t2, 16);
        float aw = e2 / t2;
        if (tid < 32)
            out[(size_t)BB * HW + (size_t)(b * DD + dl) * HW + rem] = aw;

        // argmax over D (first-max semantics), within each 32-lane half
        float bv = q; int bi = dl;
#pragma unroll
        for (int s = 1; s <= 16; s <<= 1) {
            float ov = __shfl_xor(bv, s);
            int   oi = __shfl_xor(bi, s);
            if (ov > bv || (ov == bv && oi < bi)) { bv = ov; bi = oi; }
        }
        if (tid < 32 && dl == bi) out[p] = sDep[bi];
    }
}

// ---------------------------------------------------------------------------
extern "C" void kernel_launch(void* const* d_in, const int* in_sizes, int n_in,
                              void* d_out, int out_size, void* d_ws, size_t ws_size,
                              hipStream_t stream) {
    const float* ref   = (const float*)d_in[0];  // (B,C,H,W)
    const float* src   = (const float*)d_in[1];  // (N,B,C,H,W)
    const float* proj  = (const float*)d_in[2];  // (B,N+1,2,4,4)
    const float* depth = (const float*)d_in[3];  // (B,D,H,W)
    const float* regw  = (const float*)d_in[4];  // (8,)
    const float* regb  = (const float*)d_in[5];  // (1,)
    float* out = (float*)d_out;

    float* ws   = (float*)d_ws;
    float* mats = ws;                                 // 96 floats (pad to 256)
    float* srcT = ws + 256;                           // N*B*HW*32 = 5,242,880
    float* refT = srcT + (size_t)NN * BB * HW * 32;   // B*HW*32 = 1,310,720

    prep_transpose<<<dim3(HW / 32, 10), 256, 0, stream>>>(src, ref, proj,
                                                          srcT, refT, mats);
    main_kernel<<<BB * HW, 256, 0, stream>>>(srcT, refT, depth, mats,
                                             regw, regb, out);
}

// Round 8
// 195.582 us; speedup vs baseline: 1.0572x; 1.0105x over previous
//
#include <hip/hip_runtime.h>
#include <hip/hip_bf16.h>
#include <math.h>

// Problem constants (from reference setup_inputs)
#define BB 2
#define CC 32
#define HH 128
#define WW 160
#define DD 32
#define NN 4
#define HW (HH * WW)        // 20480
#define GG 8

typedef float v2f __attribute__((ext_vector_type(2)));

// ---------------------------------------------------------------------------
// Device helper: per-(b,src) projection matrices (FP64 Gauss-Jordan).
// Executed by threads 0..7 of one block of the prep kernel.
// ---------------------------------------------------------------------------
__device__ void compute_mats(int t, const float* __restrict__ proj,
                             float* __restrict__ mats) {
    int b = t >> 2, n = t & 3;
    const float* Er = proj + ((size_t)(b * (NN + 1) + 0) * 2 + 0) * 16;
    const float* Kr = proj + ((size_t)(b * (NN + 1) + 0) * 2 + 1) * 16;
    const float* Es = proj + ((size_t)(b * (NN + 1) + n + 1) * 2 + 0) * 16;
    const float* Ks = proj + ((size_t)(b * (NN + 1) + n + 1) * 2 + 1) * 16;

    double A[4][4], Bm[4][4];
    for (int r = 0; r < 4; r++)
        for (int c = 0; c < 4; c++) {
            if (r < 3) {
                A[r][c]  = (double)Kr[r*4+0]*Er[0*4+c] + (double)Kr[r*4+1]*Er[1*4+c] + (double)Kr[r*4+2]*Er[2*4+c];
                Bm[r][c] = (double)Ks[r*4+0]*Es[0*4+c] + (double)Ks[r*4+1]*Es[1*4+c] + (double)Ks[r*4+2]*Es[2*4+c];
            } else {
                A[r][c]  = (double)Er[12 + c];
                Bm[r][c] = (double)Es[12 + c];
            }
        }
    double M[4][8];
    for (int i = 0; i < 4; i++)
        for (int j = 0; j < 4; j++) { M[i][j] = A[i][j]; M[i][4+j] = (i == j) ? 1.0 : 0.0; }
    for (int col = 0; col < 4; col++) {
        int piv = col;
        for (int r = col + 1; r < 4; r++)
            if (fabs(M[r][col]) > fabs(M[piv][col])) piv = r;
        if (piv != col)
            for (int j = 0; j < 8; j++) { double tmp = M[col][j]; M[col][j] = M[piv][j]; M[piv][j] = tmp; }
        double pv = M[col][col];
        for (int j = 0; j < 8; j++) M[col][j] /= pv;
        for (int r = 0; r < 4; r++) {
            if (r == col) continue;
            double f = M[r][col];
            for (int j = 0; j < 8; j++) M[r][j] -= f * M[col][j];
        }
    }
    float* o = mats + t * 12;
    for (int i = 0; i < 3; i++) {
        double p0 = 0, p1 = 0, p2 = 0, p3 = 0;
        for (int k = 0; k < 4; k++) {
            p0 += Bm[i][k] * M[k][4+0];
            p1 += Bm[i][k] * M[k][4+1];
            p2 += Bm[i][k] * M[k][4+2];
            p3 += Bm[i][k] * M[k][4+3];
        }
        o[i*3+0] = (float)p0; o[i*3+1] = (float)p1; o[i*3+2] = (float)p2;
        o[9 + i] = (float)p3;
    }
}

// ---------------------------------------------------------------------------
// Kernel 1: merged transpose [32][HW] -> [HW][32]; slabs 0-7 = src, 8-9 = ref.
// Block (0,0) additionally computes the 8 projection matrices (tid<8).
// ---------------------------------------------------------------------------
__global__ __launch_bounds__(256) void prep_transpose(const float* __restrict__ src,
                                                      const float* __restrict__ ref,
                                                      const float* __restrict__ proj,
                                                      float* __restrict__ srcT,
                                                      float* __restrict__ refT,
                                                      float* __restrict__ mats) {
    if (blockIdx.x == 0 && blockIdx.y == 0 && threadIdx.x < 8)
        compute_mats(threadIdx.x, proj, mats);

    __shared__ float t[32][33];
    int slab = blockIdx.y;
    const float* ip;
    float* op;
    if (slab < 8) { ip = src + (size_t)slab * 32 * HW; op = srcT + (size_t)slab * 32 * HW; }
    else          { ip = ref + (size_t)(slab - 8) * 32 * HW; op = refT + (size_t)(slab - 8) * 32 * HW; }
    int hw0 = blockIdx.x * 32;
    int tx = threadIdx.x & 31, ty = threadIdx.x >> 5;
#pragma unroll
    for (int i = 0; i < 4; i++) {
        int c = ty + i * 8;
        t[c][tx] = ip[(size_t)c * HW + hw0 + tx];
    }
    __syncthreads();
#pragma unroll
    for (int i = 0; i < 4; i++) {
        int hl = ty + i * 8;
        op[(size_t)(hw0 + hl) * 32 + tx] = t[tx][hl];
    }
}

// ---------------------------------------------------------------------------
// Kernel 2: main fused kernel. Block = 256 threads = one ref pixel.
// Thread (d,g): d = tid>>3 (depth 0..31), g = tid&7 (channel group).
// XCD swizzle: p = (bid&7)*640 + (bid>>3) so each XCD (round-robin bid%8)
// serves a contiguous 640-pixel band whose gather footprint fits its 4MiB L2.
// ---------------------------------------------------------------------------
__global__ __launch_bounds__(256) void main_kernel(
    const float* __restrict__ srcT,   // (N*B, HW, 32) channels-last
    const float* __restrict__ refT,   // (B,   HW, 32) channels-last
    const float* __restrict__ depth,  // (B, D, H, W) original layout
    const float* __restrict__ mats,   // (B*N, 12) rot row-major + trans
    const float* __restrict__ regw,   // (8,)
    const float* __restrict__ regb,   // (1,)
    float* __restrict__ out)          // [B*HW depth][B*D*HW attn]
{
    int tid = threadIdx.x;
    int g  = tid & 7;
    int d  = tid >> 3;      // 0..31

    int bid = blockIdx.x;
    int p   = (bid & 7) * ((BB * HW) / 8) + (bid >> 3);  // XCD-contiguous band
    int b   = p / HW;
    int rem = p - b * HW;
    int y   = rem / WW;
    int x   = rem - y * WW;
    float fx = (float)x, fy = (float)y;

    // this thread's group of the ref feature (one float4)
    float4 R = *(const float4*)(refT + (size_t)p * 32 + g * 4);
    v2f Rlo = { R.x, R.y }, Rhi = { R.z, R.w };
    float dep = depth[((size_t)(b * DD + d) * HH + y) * WW + x];
    float rwg = regw[g];
    float rb  = regb[0];

    __shared__ float sL[NN][DD];    // per-source logits over depth
    __shared__ float sCW[NN][DD];   // per-source softmax weights (w/ 1/sqrt(C))
    __shared__ float sCWS[DD];      // sum over sources of cw + 1e-8
    __shared__ float sE[DD];        // final logits over depth
    __shared__ float sDep[DD];      // depth hypothesis per d

    if (g == 0) sDep[d] = dep;

    // ---- Phase 0: one homography per lane, for source n0 = tid&3 at depth d
    float W00, W10, W01, W11;
    int   I00, I10, I01, I11;
    {
        int n0 = tid & 3;
        const float* Mp = mats + (size_t)(b * NN + n0) * 12;
        float4 m0 = *(const float4*)(Mp);       // rows are 48B -> 16B aligned
        float4 m1 = *(const float4*)(Mp + 4);
        float4 m2 = *(const float4*)(Mp + 8);
        float ax = m0.x * fx + m0.y * fy + m0.z;
        float ay = m0.w * fx + m1.x * fy + m1.y;
        float az = m1.z * fx + m1.w * fy + m2.x;
        float px = ax * dep + m2.y;
        float py = ay * dep + m2.z;
        float pz = az * dep + m2.w;
        float z  = (pz == 0.f) ? 1e-9f : pz;
        float rz = __builtin_amdgcn_rcpf(z);
        float gx = px * rz, gy = py * rz;

        float x0f = floorf(gx), y0f = floorf(gy);
        float wx = gx - x0f, wy = gy - y0f;
        bool vx0 = (x0f >= 0.f)  && (x0f <= (float)(WW - 1));
        bool vx1 = (x0f >= -1.f) && (x0f <= (float)(WW - 2));
        bool vy0 = (y0f >= 0.f)  && (y0f <= (float)(HH - 1));
        bool vy1 = (y0f >= -1.f) && (y0f <= (float)(HH - 2));
        W00 = (vx0 && vy0) ? (1.f - wx) * (1.f - wy) : 0.f;
        W10 = (vx1 && vy0) ? wx * (1.f - wy)         : 0.f;
        W01 = (vx0 && vy1) ? (1.f - wx) * wy         : 0.f;
        W11 = (vx1 && vy1) ? wx * wy                 : 0.f;

        int xi0 = (int)fminf(fmaxf(x0f,       0.f), (float)(WW - 1));
        int xi1 = (int)fminf(fmaxf(x0f + 1.f, 0.f), (float)(WW - 1));
        int yi0 = (int)fminf(fmaxf(y0f,       0.f), (float)(HH - 1));
        int yi1 = (int)fminf(fmaxf(y0f + 1.f, 0.f), (float)(HH - 1));
        I00 = yi0 * WW + xi0;
        I10 = yi0 * WW + xi1;
        I01 = yi1 * WW + xi0;
        I11 = yi1 * WW + xi1;
    }

    float cor[NN];

    // ---- Phase 1: gathers + packed blend/dot + octet g-sum; no barriers
#pragma unroll
    for (int n = 0; n < NN; n++) {
        int src_lane = (tid & 56) | n;     // lane holding (n, my d)
        float w00 = __shfl(W00, src_lane);
        float w10 = __shfl(W10, src_lane);
        float w01 = __shfl(W01, src_lane);
        float w11 = __shfl(W11, src_lane);
        int   i00 = __shfl(I00, src_lane);
        int   i10 = __shfl(I10, src_lane);
        int   i01 = __shfl(I01, src_lane);
        int   i11 = __shfl(I11, src_lane);

        const float4* S4 = (const float4*)(srcT + (size_t)(n * BB + b) * (32 * HW));
        float4 a  = S4[(size_t)i00 * 8 + g];
        float4 bq = S4[(size_t)i10 * 8 + g];
        float4 c  = S4[(size_t)i01 * 8 + g];
        float4 e  = S4[(size_t)i11 * 8 + g];

        // packed-fp32 blend-then-dot
        v2f alo = { a.x, a.y },  ahi = { a.z, a.w };
        v2f blo = { bq.x, bq.y }, bhi = { bq.z, bq.w };
        v2f clo = { c.x, c.y },  chi = { c.z, c.w };
        v2f elo = { e.x, e.y },  ehi = { e.z, e.w };
        v2f wlo = w00 * alo + w10 * blo + w01 * clo + w11 * elo;
        v2f whi = w00 * ahi + w10 * bhi + w01 * chi + w11 * ehi;
        v2f pr  = wlo * Rlo + whi * Rhi;
        float cr = pr.x + pr.y;
        cor[n] = cr;

        // sum over the 8 channel-groups (octet butterfly; lane-invariant)
        float ls = cr;
        ls += __shfl_xor(ls, 1);
        ls += __shfl_xor(ls, 2);
        ls += __shfl_xor(ls, 4);
        if (g == 0) sL[n][d] = ls * 0.125f;  // mean over C//G=4 then /attn_temp
    }
    __syncthreads();   // barrier 1: sL fully populated

    // ---- Stats: wave 0 computes cw[n][d] and cwsum[d] for all n,d
    if (tid < 64) {
        int n  = tid >> 4;       // 0..3
        int dh = tid & 15;       // 0..15; covers d=dh and d=dh+16
        float l0 = sL[n][dh];
        float l1 = sL[n][dh + 16];
        float m = fmaxf(l0, l1);
        m = fmaxf(m, __shfl_xor(m, 1));
        m = fmaxf(m, __shfl_xor(m, 2));
        m = fmaxf(m, __shfl_xor(m, 4));
        m = fmaxf(m, __shfl_xor(m, 8));
        float e0 = __expf(l0 - m), e1 = __expf(l1 - m);
        float s = e0 + e1;
        s += __shfl_xor(s, 1);
        s += __shfl_xor(s, 2);
        s += __shfl_xor(s, 4);
        s += __shfl_xor(s, 8);
        float f = 0.17677669529663687f / s;   // fold 1/sqrt(C=32)
        float c0 = e0 * f, c1 = e1 * f;
        sCW[n][dh]      = c0;
        sCW[n][dh + 16] = c1;
        // cross-source sum per depth (lanes with same dh across the 4 n-groups)
        float t0 = c0, t1 = c1;
        t0 += __shfl_xor(t0, 16); t0 += __shfl_xor(t0, 32);
        t1 += __shfl_xor(t1, 16); t1 += __shfl_xor(t1, 32);
        if (n == 0) {
            sCWS[dh]      = t0 + 1e-8f;
            sCWS[dh + 16] = t1 + 1e-8f;
        }
    }
    __syncthreads();   // barrier 2: sCW/sCWS ready

    // ---- Phase 2: per-thread weighted accumulation + reg projection
    float cf = 0.f;
#pragma unroll
    for (int n = 0; n < NN; n++) cf += sCW[n][d] * cor[n];
    cf *= 0.25f;                         // fold mean(C//G=4) factor
    float v = cf * rwg;
    v += __shfl_xor(v, 1);
    v += __shfl_xor(v, 2);
    v += __shfl_xor(v, 4);
    float logit2 = v * __builtin_amdgcn_rcpf(sCWS[d]) + rb;  // same across octet
    if (g == 0) sE[d] = logit2;
    __syncthreads();   // barrier 3: sE fully populated

    // ---- Final: wave 0 alone — softmax over D, attn writes, argmax depth
    if (tid < 64) {
        int dl = tid & 31;               // both wave halves compute identically
        float q = sE[dl];
        float m2 = q;
        m2 = fmaxf(m2, __shfl_xor(m2, 1));
        m2 = fmaxf(m2, __shfl_xor(m2, 2));
        m2 = fmaxf(m2, __shfl_xor(m2, 4));
        m2 = fmaxf(m2, __shfl_xor(m2, 8));
        m2 = fmaxf(m2, __shfl_xor(m2, 16));
        float e2 = __expf(q - m2);
        float t2 = e2;
        t2 += __shfl_xor(t2, 1);
        t2 += __shfl_xor(t2, 2);
        t2 += __shfl_xor(t2, 4);
        t2 += __shfl_xor(t2, 8);
        t2 += __shfl_xor(t2, 16);
        float aw = e2 / t2;
        if (tid < 32)
            out[(size_t)BB * HW + (size_t)(b * DD + dl) * HW + rem] = aw;

        // argmax over D (first-max semantics), within each 32-lane half
        float bv = q; int bi = dl;
#pragma unroll
        for (int s = 1; s <= 16; s <<= 1) {
            float ov = __shfl_xor(bv, s);
            int   oi = __shfl_xor(bi, s);
            if (ov > bv || (ov == bv && oi < bi)) { bv = ov; bi = oi; }
        }
        if (tid < 32 && dl == bi) out[p] = sDep[bi];
    }
}

// ---------------------------------------------------------------------------
extern "C" void kernel_launch(void* const* d_in, const int* in_sizes, int n_in,
                              void* d_out, int out_size, void* d_ws, size_t ws_size,
                              hipStream_t stream) {
    const float* ref   = (const float*)d_in[0];  // (B,C,H,W)
    const float* src   = (const float*)d_in[1];  // (N,B,C,H,W)
    const float* proj  = (const float*)d_in[2];  // (B,N+1,2,4,4)
    const float* depth = (const float*)d_in[3];  // (B,D,H,W)
    const float* regw  = (const float*)d_in[4];  // (8,)
    const float* regb  = (const float*)d_in[5];  // (1,)
    float* out = (float*)d_out;

    float* ws   = (float*)d_ws;
    float* mats = ws;                                 // 96 floats (pad to 256)
    float* srcT = ws + 256;                           // N*B*HW*32 = 5,242,880
    float* refT = srcT + (size_t)NN * BB * HW * 32;   // B*HW*32 = 1,310,720

    prep_transpose<<<dim3(HW / 32, 10), 256, 0, stream>>>(src, ref, proj,
                                                          srcT, refT, mats);
    main_kernel<<<BB * HW, 256, 0, stream>>>(srcT, refT, depth, mats,
                                             regw, regb, out);
}

// Round 9
// 195.406 us; speedup vs baseline: 1.0582x; 1.0009x over previous
//
#include <hip/hip_runtime.h>
#include <hip/hip_bf16.h>
#include <math.h>

// Problem constants (from reference setup_inputs)
#define BB 2
#define CC 32
#define HH 128
#define WW 160
#define DD 32
#define NN 4
#define HW (HH * WW)        // 20480
#define GG 8

typedef float v2f __attribute__((ext_vector_type(2)));

// ---------------------------------------------------------------------------
// Device helper: per-(b,src) projection matrices (FP64 Gauss-Jordan).
// Executed by threads 0..7 of one block of the prep kernel.
// ---------------------------------------------------------------------------
__device__ void compute_mats(int t, const float* __restrict__ proj,
                             float* __restrict__ mats) {
    int b = t >> 2, n = t & 3;
    const float* Er = proj + ((size_t)(b * (NN + 1) + 0) * 2 + 0) * 16;
    const float* Kr = proj + ((size_t)(b * (NN + 1) + 0) * 2 + 1) * 16;
    const float* Es = proj + ((size_t)(b * (NN + 1) + n + 1) * 2 + 0) * 16;
    const float* Ks = proj + ((size_t)(b * (NN + 1) + n + 1) * 2 + 1) * 16;

    double A[4][4], Bm[4][4];
    for (int r = 0; r < 4; r++)
        for (int c = 0; c < 4; c++) {
            if (r < 3) {
                A[r][c]  = (double)Kr[r*4+0]*Er[0*4+c] + (double)Kr[r*4+1]*Er[1*4+c] + (double)Kr[r*4+2]*Er[2*4+c];
                Bm[r][c] = (double)Ks[r*4+0]*Es[0*4+c] + (double)Ks[r*4+1]*Es[1*4+c] + (double)Ks[r*4+2]*Es[2*4+c];
            } else {
                A[r][c]  = (double)Er[12 + c];
                Bm[r][c] = (double)Es[12 + c];
            }
        }
    double M[4][8];
    for (int i = 0; i < 4; i++)
        for (int j = 0; j < 4; j++) { M[i][j] = A[i][j]; M[i][4+j] = (i == j) ? 1.0 : 0.0; }
    for (int col = 0; col < 4; col++) {
        int piv = col;
        for (int r = col + 1; r < 4; r++)
            if (fabs(M[r][col]) > fabs(M[piv][col])) piv = r;
        if (piv != col)
            for (int j = 0; j < 8; j++) { double tmp = M[col][j]; M[col][j] = M[piv][j]; M[piv][j] = tmp; }
        double pv = M[col][col];
        for (int j = 0; j < 8; j++) M[col][j] /= pv;
        for (int r = 0; r < 4; r++) {
            if (r == col) continue;
            double f = M[r][col];
            for (int j = 0; j < 8; j++) M[r][j] -= f * M[col][j];
        }
    }
    float* o = mats + t * 12;
    for (int i = 0; i < 3; i++) {
        double p0 = 0, p1 = 0, p2 = 0, p3 = 0;
        for (int k = 0; k < 4; k++) {
            p0 += Bm[i][k] * M[k][4+0];
            p1 += Bm[i][k] * M[k][4+1];
            p2 += Bm[i][k] * M[k][4+2];
            p3 += Bm[i][k] * M[k][4+3];
        }
        o[i*3+0] = (float)p0; o[i*3+1] = (float)p1; o[i*3+2] = (float)p2;
        o[9 + i] = (float)p3;
    }
}

// ---------------------------------------------------------------------------
// Kernel 1: merged transpose [32][HW] -> [HW][32]; slabs 0-7 = src, 8-9 = ref.
// Vectorized: ONE float4 global read + ONE float4 global write per thread.
//   read : thread (c = t>>3, q = t&7) loads ip[c*HW + hw0 + 4q .. +3]
//   write: thread (hl = t>>3, q = t&7) stores op[(hw0+hl)*32 + 4q .. +3]
// Block (0,0) additionally computes the 8 projection matrices (tid<8).
// ---------------------------------------------------------------------------
__global__ __launch_bounds__(256) void prep_transpose(const float* __restrict__ src,
                                                      const float* __restrict__ ref,
                                                      const float* __restrict__ proj,
                                                      float* __restrict__ srcT,
                                                      float* __restrict__ refT,
                                                      float* __restrict__ mats) {
    if (blockIdx.x == 0 && blockIdx.y == 0 && threadIdx.x < 8)
        compute_mats(threadIdx.x, proj, mats);

    __shared__ float t[32][33];
    int slab = blockIdx.y;
    const float* ip;
    float* op;
    if (slab < 8) { ip = src + (size_t)slab * 32 * HW; op = srcT + (size_t)slab * 32 * HW; }
    else          { ip = ref + (size_t)(slab - 8) * 32 * HW; op = refT + (size_t)(slab - 8) * 32 * HW; }
    int hw0 = blockIdx.x * 32;
    int tt = threadIdx.x;
    int c  = tt >> 3;            // 0..31 (channel)
    int q  = tt & 7;             // 0..7  (quad within 32)

    float4 rv = *(const float4*)(ip + (size_t)c * HW + hw0 + 4 * q);
    t[c][4 * q + 0] = rv.x;
    t[c][4 * q + 1] = rv.y;
    t[c][4 * q + 2] = rv.z;
    t[c][4 * q + 3] = rv.w;
    __syncthreads();

    int hl = tt >> 3;            // 0..31 (hw within tile)
    float4 wv;
    wv.x = t[4 * q + 0][hl];
    wv.y = t[4 * q + 1][hl];
    wv.z = t[4 * q + 2][hl];
    wv.w = t[4 * q + 3][hl];
    *(float4*)(op + (size_t)(hw0 + hl) * 32 + 4 * q) = wv;
}

// ---------------------------------------------------------------------------
// Kernel 2: main fused kernel. Block = 256 threads = one ref pixel.
// Thread (d,g): d = tid>>3 (depth 0..31), g = tid&7 (channel group).
// XCD swizzle: p = (bid&7)*640 + (bid>>3) so each XCD (round-robin bid%8)
// serves a contiguous 640-pixel band whose gather footprint fits its 4MiB L2.
// ---------------------------------------------------------------------------
__global__ __launch_bounds__(256) void main_kernel(
    const float* __restrict__ srcT,   // (N*B, HW, 32) channels-last
    const float* __restrict__ refT,   // (B,   HW, 32) channels-last
    const float* __restrict__ depth,  // (B, D, H, W) original layout
    const float* __restrict__ mats,   // (B*N, 12) rot row-major + trans
    const float* __restrict__ regw,   // (8,)
    const float* __restrict__ regb,   // (1,)
    float* __restrict__ out)          // [B*HW depth][B*D*HW attn]
{
    int tid = threadIdx.x;
    int g  = tid & 7;
    int d  = tid >> 3;      // 0..31

    int bid = blockIdx.x;
    int p   = (bid & 7) * ((BB * HW) / 8) + (bid >> 3);  // XCD-contiguous band
    int b   = p / HW;
    int rem = p - b * HW;
    int y   = rem / WW;
    int x   = rem - y * WW;
    float fx = (float)x, fy = (float)y;

    // this thread's group of the ref feature (one float4)
    float4 R = *(const float4*)(refT + (size_t)p * 32 + g * 4);
    v2f Rlo = { R.x, R.y }, Rhi = { R.z, R.w };
    float dep = depth[((size_t)(b * DD + d) * HH + y) * WW + x];
    float rwg = regw[g];
    float rb  = regb[0];

    __shared__ float sL[NN][DD];    // per-source logits over depth
    __shared__ float sCW[NN][DD];   // per-source softmax weights (w/ 1/sqrt(C))
    __shared__ float sCWS[DD];      // sum over sources of cw + 1e-8
    __shared__ float sE[DD];        // final logits over depth
    __shared__ float sDep[DD];      // depth hypothesis per d

    if (g == 0) sDep[d] = dep;

    // ---- Phase 0: one homography per lane, for source n0 = tid&3 at depth d
    float W00, W10, W01, W11;
    int   I00, I10, I01, I11;
    {
        int n0 = tid & 3;
        const float* Mp = mats + (size_t)(b * NN + n0) * 12;
        float4 m0 = *(const float4*)(Mp);       // rows are 48B -> 16B aligned
        float4 m1 = *(const float4*)(Mp + 4);
        float4 m2 = *(const float4*)(Mp + 8);
        float ax = m0.x * fx + m0.y * fy + m0.z;
        float ay = m0.w * fx + m1.x * fy + m1.y;
        float az = m1.z * fx + m1.w * fy + m2.x;
        float px = ax * dep + m2.y;
        float py = ay * dep + m2.z;
        float pz = az * dep + m2.w;
        float z  = (pz == 0.f) ? 1e-9f : pz;
        float rz = __builtin_amdgcn_rcpf(z);
        float gx = px * rz, gy = py * rz;

        float x0f = floorf(gx), y0f = floorf(gy);
        float wx = gx - x0f, wy = gy - y0f;
        bool vx0 = (x0f >= 0.f)  && (x0f <= (float)(WW - 1));
        bool vx1 = (x0f >= -1.f) && (x0f <= (float)(WW - 2));
        bool vy0 = (y0f >= 0.f)  && (y0f <= (float)(HH - 1));
        bool vy1 = (y0f >= -1.f) && (y0f <= (float)(HH - 2));
        W00 = (vx0 && vy0) ? (1.f - wx) * (1.f - wy) : 0.f;
        W10 = (vx1 && vy0) ? wx * (1.f - wy)         : 0.f;
        W01 = (vx0 && vy1) ? (1.f - wx) * wy         : 0.f;
        W11 = (vx1 && vy1) ? wx * wy                 : 0.f;

        int xi0 = (int)fminf(fmaxf(x0f,       0.f), (float)(WW - 1));
        int xi1 = (int)fminf(fmaxf(x0f + 1.f, 0.f), (float)(WW - 1));
        int yi0 = (int)fminf(fmaxf(y0f,       0.f), (float)(HH - 1));
        int yi1 = (int)fminf(fmaxf(y0f + 1.f, 0.f), (float)(HH - 1));
        I00 = yi0 * WW + xi0;
        I10 = yi0 * WW + xi1;
        I01 = yi1 * WW + xi0;
        I11 = yi1 * WW + xi1;
    }

    float cor[NN];

    // ---- Phase 1: gathers + packed blend/dot + octet g-sum; no barriers
#pragma unroll
    for (int n = 0; n < NN; n++) {
        int src_lane = (tid & 56) | n;     // lane holding (n, my d)
        float w00 = __shfl(W00, src_lane);
        float w10 = __shfl(W10, src_lane);
        float w01 = __shfl(W01, src_lane);
        float w11 = __shfl(W11, src_lane);
        int   i00 = __shfl(I00, src_lane);
        int   i10 = __shfl(I10, src_lane);
        int   i01 = __shfl(I01, src_lane);
        int   i11 = __shfl(I11, src_lane);

        const float4* S4 = (const float4*)(srcT + (size_t)(n * BB + b) * (32 * HW));
        float4 a  = S4[(size_t)i00 * 8 + g];
        float4 bq = S4[(size_t)i10 * 8 + g];
        float4 c  = S4[(size_t)i01 * 8 + g];
        float4 e  = S4[(size_t)i11 * 8 + g];

        // packed-fp32 blend-then-dot
        v2f alo = { a.x, a.y },  ahi = { a.z, a.w };
        v2f blo = { bq.x, bq.y }, bhi = { bq.z, bq.w };
        v2f clo = { c.x, c.y },  chi = { c.z, c.w };
        v2f elo = { e.x, e.y },  ehi = { e.z, e.w };
        v2f wlo = w00 * alo + w10 * blo + w01 * clo + w11 * elo;
        v2f whi = w00 * ahi + w10 * bhi + w01 * chi + w11 * ehi;
        v2f pr  = wlo * Rlo + whi * Rhi;
        float cr = pr.x + pr.y;
        cor[n] = cr;

        // sum over the 8 channel-groups (octet butterfly; lane-invariant)
        float ls = cr;
        ls += __shfl_xor(ls, 1);
        ls += __shfl_xor(ls, 2);
        ls += __shfl_xor(ls, 4);
        if (g == 0) sL[n][d] = ls * 0.125f;  // mean over C//G=4 then /attn_temp
    }
    __syncthreads();   // barrier 1: sL fully populated

    // ---- Stats: wave 0 computes cw[n][d] and cwsum[d] for all n,d
    if (tid < 64) {
        int n  = tid >> 4;       // 0..3
        int dh = tid & 15;       // 0..15; covers d=dh and d=dh+16
        float l0 = sL[n][dh];
        float l1 = sL[n][dh + 16];
        float m = fmaxf(l0, l1);
        m = fmaxf(m, __shfl_xor(m, 1));
        m = fmaxf(m, __shfl_xor(m, 2));
        m = fmaxf(m, __shfl_xor(m, 4));
        m = fmaxf(m, __shfl_xor(m, 8));
        float e0 = __expf(l0 - m), e1 = __expf(l1 - m);
        float s = e0 + e1;
        s += __shfl_xor(s, 1);
        s += __shfl_xor(s, 2);
        s += __shfl_xor(s, 4);
        s += __shfl_xor(s, 8);
        float f = 0.17677669529663687f / s;   // fold 1/sqrt(C=32)
        float c0 = e0 * f, c1 = e1 * f;
        sCW[n][dh]      = c0;
        sCW[n][dh + 16] = c1;
        // cross-source sum per depth (lanes with same dh across the 4 n-groups)
        float t0 = c0, t1 = c1;
        t0 += __shfl_xor(t0, 16); t0 += __shfl_xor(t0, 32);
        t1 += __shfl_xor(t1, 16); t1 += __shfl_xor(t1, 32);
        if (n == 0) {
            sCWS[dh]      = t0 + 1e-8f;
            sCWS[dh + 16] = t1 + 1e-8f;
        }
    }
    __syncthreads();   // barrier 2: sCW/sCWS ready

    // ---- Phase 2: per-thread weighted accumulation + reg projection
    float cf = 0.f;
#pragma unroll
    for (int n = 0; n < NN; n++) cf += sCW[n][d] * cor[n];
    cf *= 0.25f;                         // fold mean(C//G=4) factor
    float v = cf * rwg;
    v += __shfl_xor(v, 1);
    v += __shfl_xor(v, 2);
    v += __shfl_xor(v, 4);
    float logit2 = v * __builtin_amdgcn_rcpf(sCWS[d]) + rb;  // same across octet
    if (g == 0) sE[d] = logit2;
    __syncthreads();   // barrier 3: sE fully populated

    // ---- Final: wave 0 alone — softmax over D, attn writes, argmax depth
    if (tid < 64) {
        int dl = tid & 31;               // both wave halves compute identically
        float q = sE[dl];
        float m2 = q;
        m2 = fmaxf(m2, __shfl_xor(m2, 1));
        m2 = fmaxf(m2, __shfl_xor(m2, 2));
        m2 = fmaxf(m2, __shfl_xor(m2, 4));
        m2 = fmaxf(m2, __shfl_xor(m2, 8));
        m2 = fmaxf(m2, __shfl_xor(m2, 16));
        float e2 = __expf(q - m2);
        float t2 = e2;
        t2 += __shfl_xor(t2, 1);
        t2 += __shfl_xor(t2, 2);
        t2 += __shfl_xor(t2, 4);
        t2 += __shfl_xor(t2, 8);
        t2 += __shfl_xor(t2, 16);
        float aw = e2 / t2;
        if (tid < 32)
            out[(size_t)BB * HW + (size_t)(b * DD + dl) * HW + rem] = aw;

        // argmax over D (first-max semantics), within each 32-lane half
        float bv = q; int bi = dl;
#pragma unroll
        for (int s = 1; s <= 16; s <<= 1) {
            float ov = __shfl_xor(bv, s);
            int   oi = __shfl_xor(bi, s);
            if (ov > bv || (ov == bv && oi < bi)) { bv = ov; bi = oi; }
        }
        if (tid < 32 && dl == bi) out[p] = sDep[bi];
    }
}

// ---------------------------------------------------------------------------
extern "C" void kernel_launch(void* const* d_in, const int* in_sizes, int n_in,
                              void* d_out, int out_size, void* d_ws, size_t ws_size,
                              hipStream_t stream) {
    const float* ref   = (const float*)d_in[0];  // (B,C,H,W)
    const float* src   = (const float*)d_in[1];  // (N,B,C,H,W)
    const float* proj  = (const float*)d_in[2];  // (B,N+1,2,4,4)
    const float* depth = (const float*)d_in[3];  // (B,D,H,W)
    const float* regw  = (const float*)d_in[4];  // (8,)
    const float* regb  = (const float*)d_in[5];  // (1,)
    float* out = (float*)d_out;

    float* ws   = (float*)d_ws;
    float* mats = ws;                                 // 96 floats (pad to 256)
    float* srcT = ws + 256;                           // N*B*HW*32 = 5,242,880
    float* refT = srcT + (size_t)NN * BB * HW * 32;   // B*HW*32 = 1,310,720

    prep_transpose<<<dim3(HW / 32, 10), 256, 0, stream>>>(src, ref, proj,
                                                          srcT, refT, mats);
    main_kernel<<<BB * HW, 256, 0, stream>>>(srcT, refT, depth, mats,
                                             regw, regb, out);
}

// Round 10
// 191.313 us; speedup vs baseline: 1.0808x; 1.0214x over previous
//
#include <hip/hip_runtime.h>
#include <hip/hip_bf16.h>
#include <math.h>

// Problem constants (from reference setup_inputs)
#define BB 2
#define CC 32
#define HH 128
#define WW 160
#define DD 32
#define NN 4
#define HW (HH * WW)        // 20480
#define GG 8

typedef float v2f __attribute__((ext_vector_type(2)));

// ---------------------------------------------------------------------------
// Device helper: per-(b,src) projection matrices (FP64 Gauss-Jordan).
// Executed by threads 0..7 of one block of the prep kernel.
// ---------------------------------------------------------------------------
__device__ void compute_mats(int t, const float* __restrict__ proj,
                             float* __restrict__ mats) {
    int b = t >> 2, n = t & 3;
    const float* Er = proj + ((size_t)(b * (NN + 1) + 0) * 2 + 0) * 16;
    const float* Kr = proj + ((size_t)(b * (NN + 1) + 0) * 2 + 1) * 16;
    const float* Es = proj + ((size_t)(b * (NN + 1) + n + 1) * 2 + 0) * 16;
    const float* Ks = proj + ((size_t)(b * (NN + 1) + n + 1) * 2 + 1) * 16;

    double A[4][4], Bm[4][4];
    for (int r = 0; r < 4; r++)
        for (int c = 0; c < 4; c++) {
            if (r < 3) {
                A[r][c]  = (double)Kr[r*4+0]*Er[0*4+c] + (double)Kr[r*4+1]*Er[1*4+c] + (double)Kr[r*4+2]*Er[2*4+c];
                Bm[r][c] = (double)Ks[r*4+0]*Es[0*4+c] + (double)Ks[r*4+1]*Es[1*4+c] + (double)Ks[r*4+2]*Es[2*4+c];
            } else {
                A[r][c]  = (double)Er[12 + c];
                Bm[r][c] = (double)Es[12 + c];
            }
        }
    double M[4][8];
    for (int i = 0; i < 4; i++)
        for (int j = 0; j < 4; j++) { M[i][j] = A[i][j]; M[i][4+j] = (i == j) ? 1.0 : 0.0; }
    for (int col = 0; col < 4; col++) {
        int piv = col;
        for (int r = col + 1; r < 4; r++)
            if (fabs(M[r][col]) > fabs(M[piv][col])) piv = r;
        if (piv != col)
            for (int j = 0; j < 8; j++) { double tmp = M[col][j]; M[col][j] = M[piv][j]; M[piv][j] = tmp; }
        double pv = M[col][col];
        for (int j = 0; j < 8; j++) M[col][j] /= pv;
        for (int r = 0; r < 4; r++) {
            if (r == col) continue;
            double f = M[r][col];
            for (int j = 0; j < 8; j++) M[r][j] -= f * M[col][j];
        }
    }
    float* o = mats + t * 12;
    for (int i = 0; i < 3; i++) {
        double p0 = 0, p1 = 0, p2 = 0, p3 = 0;
        for (int k = 0; k < 4; k++) {
            p0 += Bm[i][k] * M[k][4+0];
            p1 += Bm[i][k] * M[k][4+1];
            p2 += Bm[i][k] * M[k][4+2];
            p3 += Bm[i][k] * M[k][4+3];
        }
        o[i*3+0] = (float)p0; o[i*3+1] = (float)p1; o[i*3+2] = (float)p2;
        o[9 + i] = (float)p3;
    }
}

// ---------------------------------------------------------------------------
// Kernel 1: merged transpose [32][HW] -> [HW][32]; slabs 0-7 = src, 8-9 = ref.
// Vectorized: ONE float4 global read + ONE float4 global write per thread.
// Block (0,0) additionally computes the 8 projection matrices (tid<8).
// ---------------------------------------------------------------------------
__global__ __launch_bounds__(256) void prep_transpose(const float* __restrict__ src,
                                                      const float* __restrict__ ref,
                                                      const float* __restrict__ proj,
                                                      float* __restrict__ srcT,
                                                      float* __restrict__ refT,
                                                      float* __restrict__ mats) {
    if (blockIdx.x == 0 && blockIdx.y == 0 && threadIdx.x < 8)
        compute_mats(threadIdx.x, proj, mats);

    __shared__ float t[32][33];
    int slab = blockIdx.y;
    const float* ip;
    float* op;
    if (slab < 8) { ip = src + (size_t)slab * 32 * HW; op = srcT + (size_t)slab * 32 * HW; }
    else          { ip = ref + (size_t)(slab - 8) * 32 * HW; op = refT + (size_t)(slab - 8) * 32 * HW; }
    int hw0 = blockIdx.x * 32;
    int tt = threadIdx.x;
    int c  = tt >> 3;            // 0..31 (channel)
    int q  = tt & 7;             // 0..7  (quad within 32)

    float4 rv = *(const float4*)(ip + (size_t)c * HW + hw0 + 4 * q);
    t[c][4 * q + 0] = rv.x;
    t[c][4 * q + 1] = rv.y;
    t[c][4 * q + 2] = rv.z;
    t[c][4 * q + 3] = rv.w;
    __syncthreads();

    int hl = tt >> 3;            // 0..31 (hw within tile)
    float4 wv;
    wv.x = t[4 * q + 0][hl];
    wv.y = t[4 * q + 1][hl];
    wv.z = t[4 * q + 2][hl];
    wv.w = t[4 * q + 3][hl];
    *(float4*)(op + (size_t)(hw0 + hl) * 32 + 4 * q) = wv;
}

// ---------------------------------------------------------------------------
// Kernel 2: main fused kernel. Block = 256 threads = one ref pixel.
// Thread (d,g): d = tid>>3 (depth 0..31), g = tid&7 (channel group).
// XCD swizzle: p = (bid&7)*640 + (bid>>3).
// W/I distribution via LDS table (2 ds_read_b128 per source) instead of
// 8 ds_bpermute shuffles per source — cuts DS-pipe ops ~2x.
// ---------------------------------------------------------------------------
__global__ __launch_bounds__(256) void main_kernel(
    const float* __restrict__ srcT,   // (N*B, HW, 32) channels-last
    const float* __restrict__ refT,   // (B,   HW, 32) channels-last
    const float* __restrict__ depth,  // (B, D, H, W) original layout
    const float* __restrict__ mats,   // (B*N, 12) rot row-major + trans
    const float* __restrict__ regw,   // (8,)
    const float* __restrict__ regb,   // (1,)
    float* __restrict__ out)          // [B*HW depth][B*D*HW attn]
{
    int tid = threadIdx.x;
    int g  = tid & 7;
    int d  = tid >> 3;      // 0..31

    int bid = blockIdx.x;
    int p   = (bid & 7) * ((BB * HW) / 8) + (bid >> 3);  // XCD-contiguous band
    int b   = p / HW;
    int rem = p - b * HW;
    int y   = rem / WW;
    int x   = rem - y * WW;
    float fx = (float)x, fy = (float)y;

    // this thread's group of the ref feature (one float4)
    float4 R = *(const float4*)(refT + (size_t)p * 32 + g * 4);
    v2f Rlo = { R.x, R.y }, Rhi = { R.z, R.w };
    float dep = depth[((size_t)(b * DD + d) * HH + y) * WW + x];
    float rwg = regw[g];
    float rb  = regb[0];

    __shared__ float4 sW[NN][DD + 1];  // bilinear weights per (n,d) (+1 pad)
    __shared__ int4   sI[NN][DD + 1];  // tap indices per (n,d)
    __shared__ float sL[NN][DD];    // per-source logits over depth
    __shared__ float sCW[NN][DD];   // per-source softmax weights (w/ 1/sqrt(C))
    __shared__ float sCWS[DD];      // sum over sources of cw + 1e-8
    __shared__ float sE[DD];        // final logits over depth
    __shared__ float sDep[DD];      // depth hypothesis per d

    if (g == 0) sDep[d] = dep;

    // ---- Phase 0: one homography per lane, for source n0 = tid&3 at depth d
    {
        int n0 = tid & 3;
        const float* Mp = mats + (size_t)(b * NN + n0) * 12;
        float4 m0 = *(const float4*)(Mp);       // rows are 48B -> 16B aligned
        float4 m1 = *(const float4*)(Mp + 4);
        float4 m2 = *(const float4*)(Mp + 8);
        float ax = m0.x * fx + m0.y * fy + m0.z;
        float ay = m0.w * fx + m1.x * fy + m1.y;
        float az = m1.z * fx + m1.w * fy + m2.x;
        float px = ax * dep + m2.y;
        float py = ay * dep + m2.z;
        float pz = az * dep + m2.w;
        float z  = (pz == 0.f) ? 1e-9f : pz;
        float rz = __builtin_amdgcn_rcpf(z);
        float gx = px * rz, gy = py * rz;

        float x0f = floorf(gx), y0f = floorf(gy);
        float wx = gx - x0f, wy = gy - y0f;
        bool vx0 = (x0f >= 0.f)  && (x0f <= (float)(WW - 1));
        bool vx1 = (x0f >= -1.f) && (x0f <= (float)(WW - 2));
        bool vy0 = (y0f >= 0.f)  && (y0f <= (float)(HH - 1));
        bool vy1 = (y0f >= -1.f) && (y0f <= (float)(HH - 2));
        float W00 = (vx0 && vy0) ? (1.f - wx) * (1.f - wy) : 0.f;
        float W10 = (vx1 && vy0) ? wx * (1.f - wy)         : 0.f;
        float W01 = (vx0 && vy1) ? (1.f - wx) * wy         : 0.f;
        float W11 = (vx1 && vy1) ? wx * wy                 : 0.f;

        int xi0 = (int)fminf(fmaxf(x0f,       0.f), (float)(WW - 1));
        int xi1 = (int)fminf(fmaxf(x0f + 1.f, 0.f), (float)(WW - 1));
        int yi0 = (int)fminf(fmaxf(y0f,       0.f), (float)(HH - 1));
        int yi1 = (int)fminf(fmaxf(y0f + 1.f, 0.f), (float)(HH - 1));

        if ((tid & 4) == 0) {   // the designated lane for (n0, d)
            sW[n0][d] = make_float4(W00, W10, W01, W11);
            sI[n0][d] = make_int4(yi0 * WW + xi0, yi0 * WW + xi1,
                                  yi1 * WW + xi0, yi1 * WW + xi1);
        }
    }
    __syncthreads();   // barrier 0: sW/sI populated

    float cor[NN];

    // ---- Phase 1: broadcast W/I reads + gathers + packed blend/dot + g-sum
#pragma unroll
    for (int n = 0; n < NN; n++) {
        float4 wv = sW[n][d];
        int4   iv = sI[n][d];

        const float4* S4 = (const float4*)(srcT + (size_t)(n * BB + b) * (32 * HW));
        float4 a  = S4[(size_t)iv.x * 8 + g];
        float4 bq = S4[(size_t)iv.y * 8 + g];
        float4 c  = S4[(size_t)iv.z * 8 + g];
        float4 e  = S4[(size_t)iv.w * 8 + g];

        // packed-fp32 blend-then-dot
        v2f alo = { a.x, a.y },  ahi = { a.z, a.w };
        v2f blo = { bq.x, bq.y }, bhi = { bq.z, bq.w };
        v2f clo = { c.x, c.y },  chi = { c.z, c.w };
        v2f elo = { e.x, e.y },  ehi = { e.z, e.w };
        v2f wlo = wv.x * alo + wv.y * blo + wv.z * clo + wv.w * elo;
        v2f whi = wv.x * ahi + wv.y * bhi + wv.z * chi + wv.w * ehi;
        v2f pr  = wlo * Rlo + whi * Rhi;
        float cr = pr.x + pr.y;
        cor[n] = cr;

        // sum over the 8 channel-groups (octet butterfly; lane-invariant)
        float ls = cr;
        ls += __shfl_xor(ls, 1);
        ls += __shfl_xor(ls, 2);
        ls += __shfl_xor(ls, 4);
        if (g == 0) sL[n][d] = ls * 0.125f;  // mean over C//G=4 then /attn_temp
    }
    __syncthreads();   // barrier 1: sL fully populated

    // ---- Stats: wave 0 computes cw[n][d] and cwsum[d] for all n,d
    if (tid < 64) {
        int n  = tid >> 4;       // 0..3
        int dh = tid & 15;       // 0..15; covers d=dh and d=dh+16
        float l0 = sL[n][dh];
        float l1 = sL[n][dh + 16];
        float m = fmaxf(l0, l1);
        m = fmaxf(m, __shfl_xor(m, 1));
        m = fmaxf(m, __shfl_xor(m, 2));
        m = fmaxf(m, __shfl_xor(m, 4));
        m = fmaxf(m, __shfl_xor(m, 8));
        float e0 = __expf(l0 - m), e1 = __expf(l1 - m);
        float s = e0 + e1;
        s += __shfl_xor(s, 1);
        s += __shfl_xor(s, 2);
        s += __shfl_xor(s, 4);
        s += __shfl_xor(s, 8);
        float f = 0.17677669529663687f / s;   // fold 1/sqrt(C=32)
        float c0 = e0 * f, c1 = e1 * f;
        sCW[n][dh]      = c0;
        sCW[n][dh + 16] = c1;
        // cross-source sum per depth (lanes with same dh across the 4 n-groups)
        float t0 = c0, t1 = c1;
        t0 += __shfl_xor(t0, 16); t0 += __shfl_xor(t0, 32);
        t1 += __shfl_xor(t1, 16); t1 += __shfl_xor(t1, 32);
        if (n == 0) {
            sCWS[dh]      = t0 + 1e-8f;
            sCWS[dh + 16] = t1 + 1e-8f;
        }
    }
    __syncthreads();   // barrier 2: sCW/sCWS ready

    // ---- Phase 2: per-thread weighted accumulation + reg projection
    float cf = 0.f;
#pragma unroll
    for (int n = 0; n < NN; n++) cf += sCW[n][d] * cor[n];
    cf *= 0.25f;                         // fold mean(C//G=4) factor
    float v = cf * rwg;
    v += __shfl_xor(v, 1);
    v += __shfl_xor(v, 2);
    v += __shfl_xor(v, 4);
    float logit2 = v * __builtin_amdgcn_rcpf(sCWS[d]) + rb;  // same across octet
    if (g == 0) sE[d] = logit2;
    __syncthreads();   // barrier 3: sE fully populated

    // ---- Final: wave 0 alone — softmax over D, attn writes, argmax depth
    if (tid < 64) {
        int dl = tid & 31;               // both wave halves compute identically
        float q = sE[dl];
        float m2 = q;
        m2 = fmaxf(m2, __shfl_xor(m2, 1));
        m2 = fmaxf(m2, __shfl_xor(m2, 2));
        m2 = fmaxf(m2, __shfl_xor(m2, 4));
        m2 = fmaxf(m2, __shfl_xor(m2, 8));
        m2 = fmaxf(m2, __shfl_xor(m2, 16));
        float e2 = __expf(q - m2);
        float t2 = e2;
        t2 += __shfl_xor(t2, 1);
        t2 += __shfl_xor(t2, 2);
        t2 += __shfl_xor(t2, 4);
        t2 += __shfl_xor(t2, 8);
        t2 += __shfl_xor(t2, 16);
        float aw = e2 / t2;
        if (tid < 32)
            out[(size_t)BB * HW + (size_t)(b * DD + dl) * HW + rem] = aw;

        // argmax over D (first-max semantics), within each 32-lane half
        float bv = q; int bi = dl;
#pragma unroll
        for (int s = 1; s <= 16; s <<= 1) {
            float ov = __shfl_xor(bv, s);
            int   oi = __shfl_xor(bi, s);
            if (ov > bv || (ov == bv && oi < bi)) { bv = ov; bi = oi; }
        }
        if (tid < 32 && dl == bi) out[p] = sDep[bi];
    }
}

// ---------------------------------------------------------------------------
extern "C" void kernel_launch(void* const* d_in, const int* in_sizes, int n_in,
                              void* d_out, int out_size, void* d_ws, size_t ws_size,
                              hipStream_t stream) {
    const float* ref   = (const float*)d_in[0];  // (B,C,H,W)
    const float* src   = (const float*)d_in[1];  // (N,B,C,H,W)
    const float* proj  = (const float*)d_in[2];  // (B,N+1,2,4,4)
    const float* depth = (const float*)d_in[3];  // (B,D,H,W)
    const float* regw  = (const float*)d_in[4];  // (8,)
    const float* regb  = (const float*)d_in[5];  // (1,)
    float* out = (float*)d_out;

    float* ws   = (float*)d_ws;
    float* mats = ws;                                 // 96 floats (pad to 256)
    float* srcT = ws + 256;                           // N*B*HW*32 = 5,242,880
    float* refT = srcT + (size_t)NN * BB * HW * 32;   // B*HW*32 = 1,310,720

    prep_transpose<<<dim3(HW / 32, 10), 256, 0, stream>>>(src, ref, proj,
                                                          srcT, refT, mats);
    main_kernel<<<BB * HW, 256, 0, stream>>>(srcT, refT, depth, mats,
                                             regw, regb, out);
}

// Round 11
// 184.417 us; speedup vs baseline: 1.1212x; 1.0374x over previous
//
#include <hip/hip_runtime.h>
#include <hip/hip_bf16.h>
#include <math.h>

// Problem constants (from reference setup_inputs)
#define BB 2
#define CC 32
#define HH 128
#define WW 160
#define DD 32
#define NN 4
#define HW (HH * WW)        // 20480
#define GG 8

typedef float v2f __attribute__((ext_vector_type(2)));

// ---------------------------------------------------------------------------
// Device helper: per-(b,src) projection matrices (FP64 Gauss-Jordan).
// Executed by threads 0..7 of one block of the prep kernel.
// ---------------------------------------------------------------------------
__device__ void compute_mats(int t, const float* __restrict__ proj,
                             float* __restrict__ mats) {
    int b = t >> 2, n = t & 3;
    const float* Er = proj + ((size_t)(b * (NN + 1) + 0) * 2 + 0) * 16;
    const float* Kr = proj + ((size_t)(b * (NN + 1) + 0) * 2 + 1) * 16;
    const float* Es = proj + ((size_t)(b * (NN + 1) + n + 1) * 2 + 0) * 16;
    const float* Ks = proj + ((size_t)(b * (NN + 1) + n + 1) * 2 + 1) * 16;

    double A[4][4], Bm[4][4];
    for (int r = 0; r < 4; r++)
        for (int c = 0; c < 4; c++) {
            if (r < 3) {
                A[r][c]  = (double)Kr[r*4+0]*Er[0*4+c] + (double)Kr[r*4+1]*Er[1*4+c] + (double)Kr[r*4+2]*Er[2*4+c];
                Bm[r][c] = (double)Ks[r*4+0]*Es[0*4+c] + (double)Ks[r*4+1]*Es[1*4+c] + (double)Ks[r*4+2]*Es[2*4+c];
            } else {
                A[r][c]  = (double)Er[12 + c];
                Bm[r][c] = (double)Es[12 + c];
            }
        }
    double M[4][8];
    for (int i = 0; i < 4; i++)
        for (int j = 0; j < 4; j++) { M[i][j] = A[i][j]; M[i][4+j] = (i == j) ? 1.0 : 0.0; }
    for (int col = 0; col < 4; col++) {
        int piv = col;
        for (int r = col + 1; r < 4; r++)
            if (fabs(M[r][col]) > fabs(M[piv][col])) piv = r;
        if (piv != col)
            for (int j = 0; j < 8; j++) { double tmp = M[col][j]; M[col][j] = M[piv][j]; M[piv][j] = tmp; }
        double pv = M[col][col];
        for (int j = 0; j < 8; j++) M[col][j] /= pv;
        for (int r = 0; r < 4; r++) {
            if (r == col) continue;
            double f = M[r][col];
            for (int j = 0; j < 8; j++) M[r][j] -= f * M[col][j];
        }
    }
    float* o = mats + t * 12;
    for (int i = 0; i < 3; i++) {
        double p0 = 0, p1 = 0, p2 = 0, p3 = 0;
        for (int k = 0; k < 4; k++) {
            p0 += Bm[i][k] * M[k][4+0];
            p1 += Bm[i][k] * M[k][4+1];
            p2 += Bm[i][k] * M[k][4+2];
            p3 += Bm[i][k] * M[k][4+3];
        }
        o[i*3+0] = (float)p0; o[i*3+1] = (float)p1; o[i*3+2] = (float)p2;
        o[9 + i] = (float)p3;
    }
}

// ---------------------------------------------------------------------------
// Kernel 1: merged transpose [32][HW] -> [HW][32]; slabs 0-7 = src, 8-9 = ref.
// Vectorized: ONE float4 global read + ONE float4 global write per thread.
// Block (0,0) additionally computes the 8 projection matrices (tid<8).
// ---------------------------------------------------------------------------
__global__ __launch_bounds__(256) void prep_transpose(const float* __restrict__ src,
                                                      const float* __restrict__ ref,
                                                      const float* __restrict__ proj,
                                                      float* __restrict__ srcT,
                                                      float* __restrict__ refT,
                                                      float* __restrict__ mats) {
    if (blockIdx.x == 0 && blockIdx.y == 0 && threadIdx.x < 8)
        compute_mats(threadIdx.x, proj, mats);

    __shared__ float t[32][33];
    int slab = blockIdx.y;
    const float* ip;
    float* op;
    if (slab < 8) { ip = src + (size_t)slab * 32 * HW; op = srcT + (size_t)slab * 32 * HW; }
    else          { ip = ref + (size_t)(slab - 8) * 32 * HW; op = refT + (size_t)(slab - 8) * 32 * HW; }
    int hw0 = blockIdx.x * 32;
    int tt = threadIdx.x;
    int c  = tt >> 3;            // 0..31 (channel)
    int q  = tt & 7;             // 0..7  (quad within 32)

    float4 rv = *(const float4*)(ip + (size_t)c * HW + hw0 + 4 * q);
    t[c][4 * q + 0] = rv.x;
    t[c][4 * q + 1] = rv.y;
    t[c][4 * q + 2] = rv.z;
    t[c][4 * q + 3] = rv.w;
    __syncthreads();

    int hl = tt >> 3;            // 0..31 (hw within tile)
    float4 wv;
    wv.x = t[4 * q + 0][hl];
    wv.y = t[4 * q + 1][hl];
    wv.z = t[4 * q + 2][hl];
    wv.w = t[4 * q + 3][hl];
    *(float4*)(op + (size_t)(hw0 + hl) * 32 + 4 * q) = wv;
}

// ---------------------------------------------------------------------------
// Kernel 2: main fused kernel. Block = 256 threads = one ref pixel.
// Thread (d,g): d = tid>>3 (depth 0..31), g = tid&7 (channel group).
// XCD swizzle: p = (bid&7)*640 + (bid>>3).
// Phase 0 runs on waves 0-1 only (tid<128): dd = tid>>2, n0 = tid&3 —
// exactly one thread per (n,d); waves 2-3 skip it (wave-uniform branch).
// Indices stored pre-scaled (*8) so gather addressing is one lshl_add.
// Stats write a transposed float4 cw table (0.25 pre-folded) for phase 2.
// ---------------------------------------------------------------------------
__global__ __launch_bounds__(256) void main_kernel(
    const float* __restrict__ srcT,   // (N*B, HW, 32) channels-last
    const float* __restrict__ refT,   // (B,   HW, 32) channels-last
    const float* __restrict__ depth,  // (B, D, H, W) original layout
    const float* __restrict__ mats,   // (B*N, 12) rot row-major + trans
    const float* __restrict__ regw,   // (8,)
    const float* __restrict__ regb,   // (1,)
    float* __restrict__ out)          // [B*HW depth][B*D*HW attn]
{
    int tid = threadIdx.x;
    int g  = tid & 7;
    int d  = tid >> 3;      // 0..31

    int bid = blockIdx.x;
    int p   = (bid & 7) * ((BB * HW) / 8) + (bid >> 3);  // XCD-contiguous band
    int b   = p / HW;
    int rem = p - b * HW;
    int y   = rem / WW;
    int x   = rem - y * WW;

    // this thread's group of the ref feature (one float4)
    float4 R = *(const float4*)(refT + (size_t)p * 32 + g * 4);
    v2f Rlo = { R.x, R.y }, Rhi = { R.z, R.w };
    float rwg = regw[g];
    float rb  = regb[0];

    __shared__ float4 sW[NN][DD];      // bilinear weights per (n,d)
    __shared__ int4   sI[NN][DD];      // pre-scaled (*8) tap indices per (n,d)
    __shared__ float  sL[NN][DD];      // per-source logits over depth
    __shared__ float4 sCWT[DD];        // per-depth cw[4 sources] * 0.25
    __shared__ float  sCWS[DD];        // sum over sources of cw + 1e-8
    __shared__ float  sE[DD];          // final logits over depth
    __shared__ float  sDep[DD];        // depth hypothesis per d

    // ---- Phase 0 (waves 0-1 only): one thread per (n0, dd) homography
    if (tid < 128) {
        int n0 = tid & 3;
        int dd = tid >> 2;            // 0..31
        float fx = (float)x, fy = (float)y;
        float depM = depth[((size_t)(b * DD + dd) * HH + y) * WW + x];
        const float* Mp = mats + (size_t)(b * NN + n0) * 12;
        float4 m0 = *(const float4*)(Mp);       // rows are 48B -> 16B aligned
        float4 m1 = *(const float4*)(Mp + 4);
        float4 m2 = *(const float4*)(Mp + 8);
        float ax = m0.x * fx + m0.y * fy + m0.z;
        float ay = m0.w * fx + m1.x * fy + m1.y;
        float az = m1.z * fx + m1.w * fy + m2.x;
        float px = ax * depM + m2.y;
        float py = ay * depM + m2.z;
        float pz = az * depM + m2.w;
        float z  = (pz == 0.f) ? 1e-9f : pz;
        float rz = __builtin_amdgcn_rcpf(z);
        float gx = px * rz, gy = py * rz;

        float x0f = floorf(gx), y0f = floorf(gy);
        float wx = gx - x0f, wy = gy - y0f;
        bool vx0 = (x0f >= 0.f)  && (x0f <= (float)(WW - 1));
        bool vx1 = (x0f >= -1.f) && (x0f <= (float)(WW - 2));
        bool vy0 = (y0f >= 0.f)  && (y0f <= (float)(HH - 1));
        bool vy1 = (y0f >= -1.f) && (y0f <= (float)(HH - 2));
        float W00 = (vx0 && vy0) ? (1.f - wx) * (1.f - wy) : 0.f;
        float W10 = (vx1 && vy0) ? wx * (1.f - wy)         : 0.f;
        float W01 = (vx0 && vy1) ? (1.f - wx) * wy         : 0.f;
        float W11 = (vx1 && vy1) ? wx * wy                 : 0.f;

        int xi0 = (int)fminf(fmaxf(x0f,       0.f), (float)(WW - 1));
        int xi1 = (int)fminf(fmaxf(x0f + 1.f, 0.f), (float)(WW - 1));
        int yi0 = (int)fminf(fmaxf(y0f,       0.f), (float)(HH - 1));
        int yi1 = (int)fminf(fmaxf(y0f + 1.f, 0.f), (float)(HH - 1));

        sW[n0][dd] = make_float4(W00, W10, W01, W11);
        sI[n0][dd] = make_int4((yi0 * WW + xi0) * 8, (yi0 * WW + xi1) * 8,
                               (yi1 * WW + xi0) * 8, (yi1 * WW + xi1) * 8);
        if (n0 == 0) sDep[dd] = depM;
    }
    __syncthreads();   // barrier 0: sW/sI/sDep populated

    float cor[NN];

    // ---- Phase 1: broadcast W/I reads + gathers + packed blend/dot + g-sum
#pragma unroll
    for (int n = 0; n < NN; n++) {
        float4 wv = sW[n][d];
        int4   iv = sI[n][d];

        // stream base includes +g so tap address = base + iv (pre-scaled *8)
        const float4* S4g = (const float4*)(srcT + (size_t)(n * BB + b) * (32 * HW)) + g;
        float4 a  = S4g[iv.x];
        float4 bq = S4g[iv.y];
        float4 c  = S4g[iv.z];
        float4 e  = S4g[iv.w];

        // packed-fp32 blend-then-dot
        v2f alo = { a.x, a.y },  ahi = { a.z, a.w };
        v2f blo = { bq.x, bq.y }, bhi = { bq.z, bq.w };
        v2f clo = { c.x, c.y },  chi = { c.z, c.w };
        v2f elo = { e.x, e.y },  ehi = { e.z, e.w };
        v2f wlo = wv.x * alo + wv.y * blo + wv.z * clo + wv.w * elo;
        v2f whi = wv.x * ahi + wv.y * bhi + wv.z * chi + wv.w * ehi;
        v2f pr  = wlo * Rlo + whi * Rhi;
        float cr = pr.x + pr.y;
        cor[n] = cr;

        // sum over the 8 channel-groups (octet butterfly; lane-invariant)
        float ls = cr;
        ls += __shfl_xor(ls, 1);
        ls += __shfl_xor(ls, 2);
        ls += __shfl_xor(ls, 4);
        if (g == 0) sL[n][d] = ls * 0.125f;  // mean over C//G=4 then /attn_temp
    }
    __syncthreads();   // barrier 1: sL fully populated

    // ---- Stats: wave 0 computes cw tables for all n,d
    if (tid < 64) {
        int n  = tid >> 4;       // 0..3
        int dh = tid & 15;       // 0..15; covers d=dh and d=dh+16
        float l0 = sL[n][dh];
        float l1 = sL[n][dh + 16];
        float m = fmaxf(l0, l1);
        m = fmaxf(m, __shfl_xor(m, 1));
        m = fmaxf(m, __shfl_xor(m, 2));
        m = fmaxf(m, __shfl_xor(m, 4));
        m = fmaxf(m, __shfl_xor(m, 8));
        float e0 = __expf(l0 - m), e1 = __expf(l1 - m);
        float s = e0 + e1;
        s += __shfl_xor(s, 1);
        s += __shfl_xor(s, 2);
        s += __shfl_xor(s, 4);
        s += __shfl_xor(s, 8);
        float f = 0.17677669529663687f / s;   // fold 1/sqrt(C=32)
        float c0 = e0 * f, c1 = e1 * f;
        // transposed, 0.25 (mean over C//G=4) pre-folded for phase 2's b128 read
        ((float*)&sCWT[dh])[n]      = c0 * 0.25f;
        ((float*)&sCWT[dh + 16])[n] = c1 * 0.25f;
        // cross-source sum per depth (lanes with same dh across the 4 n-groups)
        float t0 = c0, t1 = c1;
        t0 += __shfl_xor(t0, 16); t0 += __shfl_xor(t0, 32);
        t1 += __shfl_xor(t1, 16); t1 += __shfl_xor(t1, 32);
        if (n == 0) {
            sCWS[dh]      = t0 + 1e-8f;
            sCWS[dh + 16] = t1 + 1e-8f;
        }
    }
    __syncthreads();   // barrier 2: sCWT/sCWS ready

    // ---- Phase 2: per-thread weighted accumulation + reg projection
    float4 cwv = sCWT[d];
    float cf = cwv.x * cor[0] + cwv.y * cor[1] + cwv.z * cor[2] + cwv.w * cor[3];
    float v = cf * rwg;
    v += __shfl_xor(v, 1);
    v += __shfl_xor(v, 2);
    v += __shfl_xor(v, 4);
    float logit2 = v * __builtin_amdgcn_rcpf(sCWS[d]) + rb;  // same across octet
    if (g == 0) sE[d] = logit2;
    __syncthreads();   // barrier 3: sE fully populated

    // ---- Final: wave 0 alone — softmax over D, attn writes, argmax depth
    if (tid < 64) {
        int dl = tid & 31;               // both wave halves compute identically
        float q = sE[dl];
        float m2 = q;
        m2 = fmaxf(m2, __shfl_xor(m2, 1));
        m2 = fmaxf(m2, __shfl_xor(m2, 2));
        m2 = fmaxf(m2, __shfl_xor(m2, 4));
        m2 = fmaxf(m2, __shfl_xor(m2, 8));
        m2 = fmaxf(m2, __shfl_xor(m2, 16));
        float e2 = __expf(q - m2);
        float t2 = e2;
        t2 += __shfl_xor(t2, 1);
        t2 += __shfl_xor(t2, 2);
        t2 += __shfl_xor(t2, 4);
        t2 += __shfl_xor(t2, 8);
        t2 += __shfl_xor(t2, 16);
        float aw = e2 / t2;
        if (tid < 32)
            out[(size_t)BB * HW + (size_t)(b * DD + dl) * HW + rem] = aw;

        // argmax over D (first-max semantics), within each 32-lane half
        float bv = q; int bi = dl;
#pragma unroll
        for (int s = 1; s <= 16; s <<= 1) {
            float ov = __shfl_xor(bv, s);
            int   oi = __shfl_xor(bi, s);
            if (ov > bv || (ov == bv && oi < bi)) { bv = ov; bi = oi; }
        }
        if (tid < 32 && dl == bi) out[p] = sDep[bi];
    }
}

// ---------------------------------------------------------------------------
extern "C" void kernel_launch(void* const* d_in, const int* in_sizes, int n_in,
                              void* d_out, int out_size, void* d_ws, size_t ws_size,
                              hipStream_t stream) {
    const float* ref   = (const float*)d_in[0];  // (B,C,H,W)
    const float* src   = (const float*)d_in[1];  // (N,B,C,H,W)
    const float* proj  = (const float*)d_in[2];  // (B,N+1,2,4,4)
    const float* depth = (const float*)d_in[3];  // (B,D,H,W)
    const float* regw  = (const float*)d_in[4];  // (8,)
    const float* regb  = (const float*)d_in[5];  // (1,)
    float* out = (float*)d_out;

    float* ws   = (float*)d_ws;
    float* mats = ws;                                 // 96 floats (pad to 256)
    float* srcT = ws + 256;                           // N*B*HW*32 = 5,242,880
    float* refT = srcT + (size_t)NN * BB * HW * 32;   // B*HW*32 = 1,310,720

    prep_transpose<<<dim3(HW / 32, 10), 256, 0, stream>>>(src, ref, proj,
                                                          srcT, refT, mats);
    main_kernel<<<BB * HW, 256, 0, stream>>>(srcT, refT, depth, mats,
                                             regw, regb, out);
}

// Round 12
// 184.334 us; speedup vs baseline: 1.1217x; 1.0004x over previous
//
#include <hip/hip_runtime.h>
#include <hip/hip_bf16.h>
#include <math.h>

// Problem constants (from reference setup_inputs)
#define BB 2
#define CC 32
#define HH 128
#define WW 160
#define DD 32
#define NN 4
#define HW (HH * WW)        // 20480
#define GG 8

typedef float v2f __attribute__((ext_vector_type(2)));

// ---------------------------------------------------------------------------
// Device helper: per-(b,src) projection matrices (FP64 Gauss-Jordan).
// Executed by threads 0..7 of one block of the prep kernel.
// ---------------------------------------------------------------------------
__device__ void compute_mats(int t, const float* __restrict__ proj,
                             float* __restrict__ mats) {
    int b = t >> 2, n = t & 3;
    const float* Er = proj + ((size_t)(b * (NN + 1) + 0) * 2 + 0) * 16;
    const float* Kr = proj + ((size_t)(b * (NN + 1) + 0) * 2 + 1) * 16;
    const float* Es = proj + ((size_t)(b * (NN + 1) + n + 1) * 2 + 0) * 16;
    const float* Ks = proj + ((size_t)(b * (NN + 1) + n + 1) * 2 + 1) * 16;

    double A[4][4], Bm[4][4];
    for (int r = 0; r < 4; r++)
        for (int c = 0; c < 4; c++) {
            if (r < 3) {
                A[r][c]  = (double)Kr[r*4+0]*Er[0*4+c] + (double)Kr[r*4+1]*Er[1*4+c] + (double)Kr[r*4+2]*Er[2*4+c];
                Bm[r][c] = (double)Ks[r*4+0]*Es[0*4+c] + (double)Ks[r*4+1]*Es[1*4+c] + (double)Ks[r*4+2]*Es[2*4+c];
            } else {
                A[r][c]  = (double)Er[12 + c];
                Bm[r][c] = (double)Es[12 + c];
            }
        }
    double M[4][8];
    for (int i = 0; i < 4; i++)
        for (int j = 0; j < 4; j++) { M[i][j] = A[i][j]; M[i][4+j] = (i == j) ? 1.0 : 0.0; }
    for (int col = 0; col < 4; col++) {
        int piv = col;
        for (int r = col + 1; r < 4; r++)
            if (fabs(M[r][col]) > fabs(M[piv][col])) piv = r;
        if (piv != col)
            for (int j = 0; j < 8; j++) { double tmp = M[col][j]; M[col][j] = M[piv][j]; M[piv][j] = tmp; }
        double pv = M[col][col];
        for (int j = 0; j < 8; j++) M[col][j] /= pv;
        for (int r = 0; r < 4; r++) {
            if (r == col) continue;
            double f = M[r][col];
            for (int j = 0; j < 8; j++) M[r][j] -= f * M[col][j];
        }
    }
    float* o = mats + t * 12;
    for (int i = 0; i < 3; i++) {
        double p0 = 0, p1 = 0, p2 = 0, p3 = 0;
        for (int k = 0; k < 4; k++) {
            p0 += Bm[i][k] * M[k][4+0];
            p1 += Bm[i][k] * M[k][4+1];
            p2 += Bm[i][k] * M[k][4+2];
            p3 += Bm[i][k] * M[k][4+3];
        }
        o[i*3+0] = (float)p0; o[i*3+1] = (float)p1; o[i*3+2] = (float)p2;
        o[9 + i] = (float)p3;
    }
}

// ---------------------------------------------------------------------------
// Kernel 1: merged transpose [32][HW] -> [HW][32]; slabs 0-7 = src, 8-9 = ref.
// Vectorized: ONE float4 global read + ONE float4 global write per thread.
// Block (0,0) additionally computes the 8 projection matrices (tid<8).
// ---------------------------------------------------------------------------
__global__ __launch_bounds__(256) void prep_transpose(const float* __restrict__ src,
                                                      const float* __restrict__ ref,
                                                      const float* __restrict__ proj,
                                                      float* __restrict__ srcT,
                                                      float* __restrict__ refT,
                                                      float* __restrict__ mats) {
    if (blockIdx.x == 0 && blockIdx.y == 0 && threadIdx.x < 8)
        compute_mats(threadIdx.x, proj, mats);

    __shared__ float t[32][33];
    int slab = blockIdx.y;
    const float* ip;
    float* op;
    if (slab < 8) { ip = src + (size_t)slab * 32 * HW; op = srcT + (size_t)slab * 32 * HW; }
    else          { ip = ref + (size_t)(slab - 8) * 32 * HW; op = refT + (size_t)(slab - 8) * 32 * HW; }
    int hw0 = blockIdx.x * 32;
    int tt = threadIdx.x;
    int c  = tt >> 3;            // 0..31 (channel)
    int q  = tt & 7;             // 0..7  (quad within 32)

    float4 rv = *(const float4*)(ip + (size_t)c * HW + hw0 + 4 * q);
    t[c][4 * q + 0] = rv.x;
    t[c][4 * q + 1] = rv.y;
    t[c][4 * q + 2] = rv.z;
    t[c][4 * q + 3] = rv.w;
    __syncthreads();

    int hl = tt >> 3;            // 0..31 (hw within tile)
    float4 wv;
    wv.x = t[4 * q + 0][hl];
    wv.y = t[4 * q + 1][hl];
    wv.z = t[4 * q + 2][hl];
    wv.w = t[4 * q + 3][hl];
    *(float4*)(op + (size_t)(hw0 + hl) * 32 + 4 * q) = wv;
}

// ---------------------------------------------------------------------------
// Kernel 2: main fused kernel. Block = 256 threads = one ref pixel.
// Thread (d,g): d = tid>>3 (depth 0..31), g = tid&7 (channel group).
// XCD swizzle: p = (bid&7)*640 + (bid>>3).
// sW/sI padded [NN][DD+1]: phase-0 b128 stores land in distinct bank groups
// per n0 (bank = (4n0+4dd)%32) — R11's unpadded layout was 4-way conflicted.
// sL padded [NN][DD+8]: stats reads at most 2-way (free).
// ---------------------------------------------------------------------------
__global__ __launch_bounds__(256) void main_kernel(
    const float* __restrict__ srcT,   // (N*B, HW, 32) channels-last
    const float* __restrict__ refT,   // (B,   HW, 32) channels-last
    const float* __restrict__ depth,  // (B, D, H, W) original layout
    const float* __restrict__ mats,   // (B*N, 12) rot row-major + trans
    const float* __restrict__ regw,   // (8,)
    const float* __restrict__ regb,   // (1,)
    float* __restrict__ out)          // [B*HW depth][B*D*HW attn]
{
    int tid = threadIdx.x;
    int g  = tid & 7;
    int d  = tid >> 3;      // 0..31

    int bid = blockIdx.x;
    int p   = (bid & 7) * ((BB * HW) / 8) + (bid >> 3);  // XCD-contiguous band
    int b   = p / HW;
    int rem = p - b * HW;
    int y   = rem / WW;
    int x   = rem - y * WW;

    // this thread's group of the ref feature (one float4)
    float4 R = *(const float4*)(refT + (size_t)p * 32 + g * 4);
    v2f Rlo = { R.x, R.y }, Rhi = { R.z, R.w };
    float rwg = regw[g];
    float rb  = regb[0];

    __shared__ float4 sW[NN][DD + 1];  // bilinear weights per (n,d), padded
    __shared__ int4   sI[NN][DD + 1];  // pre-scaled (*8) tap indices, padded
    __shared__ float  sL[NN][DD + 8];  // per-source logits over depth, padded
    __shared__ float4 sCWT[DD];        // per-depth cw[4 sources] * 0.25
    __shared__ float  sCWS[DD];        // sum over sources of cw + 1e-8
    __shared__ float  sE[DD];          // final logits over depth
    __shared__ float  sDep[DD];        // depth hypothesis per d

    // ---- Phase 0 (waves 0-1 only): one thread per (n0, dd) homography
    if (tid < 128) {
        int n0 = tid & 3;
        int dd = tid >> 2;            // 0..31
        float fx = (float)x, fy = (float)y;
        float depM = depth[((size_t)(b * DD + dd) * HH + y) * WW + x];
        const float* Mp = mats + (size_t)(b * NN + n0) * 12;
        float4 m0 = *(const float4*)(Mp);       // rows are 48B -> 16B aligned
        float4 m1 = *(const float4*)(Mp + 4);
        float4 m2 = *(const float4*)(Mp + 8);
        float ax = m0.x * fx + m0.y * fy + m0.z;
        float ay = m0.w * fx + m1.x * fy + m1.y;
        float az = m1.z * fx + m1.w * fy + m2.x;
        float px = ax * depM + m2.y;
        float py = ay * depM + m2.z;
        float pz = az * depM + m2.w;
        float z  = (pz == 0.f) ? 1e-9f : pz;
        float rz = __builtin_amdgcn_rcpf(z);
        float gx = px * rz, gy = py * rz;

        float x0f = floorf(gx), y0f = floorf(gy);
        float wx = gx - x0f, wy = gy - y0f;
        bool vx0 = (x0f >= 0.f)  && (x0f <= (float)(WW - 1));
        bool vx1 = (x0f >= -1.f) && (x0f <= (float)(WW - 2));
        bool vy0 = (y0f >= 0.f)  && (y0f <= (float)(HH - 1));
        bool vy1 = (y0f >= -1.f) && (y0f <= (float)(HH - 2));
        float W00 = (vx0 && vy0) ? (1.f - wx) * (1.f - wy) : 0.f;
        float W10 = (vx1 && vy0) ? wx * (1.f - wy)         : 0.f;
        float W01 = (vx0 && vy1) ? (1.f - wx) * wy         : 0.f;
        float W11 = (vx1 && vy1) ? wx * wy                 : 0.f;

        int xi0 = (int)fminf(fmaxf(x0f,       0.f), (float)(WW - 1));
        int xi1 = (int)fminf(fmaxf(x0f + 1.f, 0.f), (float)(WW - 1));
        int yi0 = (int)fminf(fmaxf(y0f,       0.f), (float)(HH - 1));
        int yi1 = (int)fminf(fmaxf(y0f + 1.f, 0.f), (float)(HH - 1));

        sW[n0][dd] = make_float4(W00, W10, W01, W11);
        sI[n0][dd] = make_int4((yi0 * WW + xi0) * 8, (yi0 * WW + xi1) * 8,
                               (yi1 * WW + xi0) * 8, (yi1 * WW + xi1) * 8);
        if (n0 == 0) sDep[dd] = depM;
    }
    __syncthreads();   // barrier 0: sW/sI/sDep populated

    float cor[NN];

    // ---- Phase 1: broadcast W/I reads + gathers + packed blend/dot + g-sum
#pragma unroll
    for (int n = 0; n < NN; n++) {
        float4 wv = sW[n][d];
        int4   iv = sI[n][d];

        // stream base includes +g so tap address = base + iv (pre-scaled *8)
        const float4* S4g = (const float4*)(srcT + (size_t)(n * BB + b) * (32 * HW)) + g;
        float4 a  = S4g[iv.x];
        float4 bq = S4g[iv.y];
        float4 c  = S4g[iv.z];
        float4 e  = S4g[iv.w];

        // packed-fp32 blend-then-dot
        v2f alo = { a.x, a.y },  ahi = { a.z, a.w };
        v2f blo = { bq.x, bq.y }, bhi = { bq.z, bq.w };
        v2f clo = { c.x, c.y },  chi = { c.z, c.w };
        v2f elo = { e.x, e.y },  ehi = { e.z, e.w };
        v2f wlo = wv.x * alo + wv.y * blo + wv.z * clo + wv.w * elo;
        v2f whi = wv.x * ahi + wv.y * bhi + wv.z * chi + wv.w * ehi;
        v2f pr  = wlo * Rlo + whi * Rhi;
        float cr = pr.x + pr.y;
        cor[n] = cr;

        // sum over the 8 channel-groups (octet butterfly; lane-invariant)
        float ls = cr;
        ls += __shfl_xor(ls, 1);
        ls += __shfl_xor(ls, 2);
        ls += __shfl_xor(ls, 4);
        if (g == 0) sL[n][d] = ls * 0.125f;  // mean over C//G=4 then /attn_temp
    }
    __syncthreads();   // barrier 1: sL fully populated

    // ---- Stats: wave 0 computes cw tables for all n,d
    if (tid < 64) {
        int n  = tid >> 4;       // 0..3
        int dh = tid & 15;       // 0..15; covers d=dh and d=dh+16
        float l0 = sL[n][dh];
        float l1 = sL[n][dh + 16];
        float m = fmaxf(l0, l1);
        m = fmaxf(m, __shfl_xor(m, 1));
        m = fmaxf(m, __shfl_xor(m, 2));
        m = fmaxf(m, __shfl_xor(m, 4));
        m = fmaxf(m, __shfl_xor(m, 8));
        float e0 = __expf(l0 - m), e1 = __expf(l1 - m);
        float s = e0 + e1;
        s += __shfl_xor(s, 1);
        s += __shfl_xor(s, 2);
        s += __shfl_xor(s, 4);
        s += __shfl_xor(s, 8);
        float f = 0.17677669529663687f / s;   // fold 1/sqrt(C=32)
        float c0 = e0 * f, c1 = e1 * f;
        // transposed, 0.25 (mean over C//G=4) pre-folded for phase 2's b128 read
        ((float*)&sCWT[dh])[n]      = c0 * 0.25f;
        ((float*)&sCWT[dh + 16])[n] = c1 * 0.25f;
        // cross-source sum per depth (lanes with same dh across the 4 n-groups)
        float t0 = c0, t1 = c1;
        t0 += __shfl_xor(t0, 16); t0 += __shfl_xor(t0, 32);
        t1 += __shfl_xor(t1, 16); t1 += __shfl_xor(t1, 32);
        if (n == 0) {
            sCWS[dh]      = t0 + 1e-8f;
            sCWS[dh + 16] = t1 + 1e-8f;
        }
    }
    __syncthreads();   // barrier 2: sCWT/sCWS ready

    // ---- Phase 2: per-thread weighted accumulation + reg projection
    float4 cwv = sCWT[d];
    float cf = cwv.x * cor[0] + cwv.y * cor[1] + cwv.z * cor[2] + cwv.w * cor[3];
    float v = cf * rwg;
    v += __shfl_xor(v, 1);
    v += __shfl_xor(v, 2);
    v += __shfl_xor(v, 4);
    float logit2 = v * __builtin_amdgcn_rcpf(sCWS[d]) + rb;  // same across octet
    if (g == 0) sE[d] = logit2;
    __syncthreads();   // barrier 3: sE fully populated

    // ---- Final: wave 0 alone — softmax over D, attn writes, argmax depth
    if (tid < 64) {
        int dl = tid & 31;               // both wave halves compute identically
        float q = sE[dl];
        float m2 = q;
        m2 = fmaxf(m2, __shfl_xor(m2, 1));
        m2 = fmaxf(m2, __shfl_xor(m2, 2));
        m2 = fmaxf(m2, __shfl_xor(m2, 4));
        m2 = fmaxf(m2, __shfl_xor(m2, 8));
        m2 = fmaxf(m2, __shfl_xor(m2, 16));
        float e2 = __expf(q - m2);
        float t2 = e2;
        t2 += __shfl_xor(t2, 1);
        t2 += __shfl_xor(t2, 2);
        t2 += __shfl_xor(t2, 4);
        t2 += __shfl_xor(t2, 8);
        t2 += __shfl_xor(t2, 16);
        float aw = e2 / t2;
        if (tid < 32)
            out[(size_t)BB * HW + (size_t)(b * DD + dl) * HW + rem] = aw;

        // argmax over D (first-max semantics), within each 32-lane half
        float bv = q; int bi = dl;
#pragma unroll
        for (int s = 1; s <= 16; s <<= 1) {
            float ov = __shfl_xor(bv, s);
            int   oi = __shfl_xor(bi, s);
            if (ov > bv || (ov == bv && oi < bi)) { bv = ov; bi = oi; }
        }
        if (tid < 32 && dl == bi) out[p] = sDep[bi];
    }
}

// ---------------------------------------------------------------------------
extern "C" void kernel_launch(void* const* d_in, const int* in_sizes, int n_in,
                              void* d_out, int out_size, void* d_ws, size_t ws_size,
                              hipStream_t stream) {
    const float* ref   = (const float*)d_in[0];  // (B,C,H,W)
    const float* src   = (const float*)d_in[1];  // (N,B,C,H,W)
    const float* proj  = (const float*)d_in[2];  // (B,N+1,2,4,4)
    const float* depth = (const float*)d_in[3];  // (B,D,H,W)
    const float* regw  = (const float*)d_in[4];  // (8,)
    const float* regb  = (const float*)d_in[5];  // (1,)
    float* out = (float*)d_out;

    float* ws   = (float*)d_ws;
    float* mats = ws;                                 // 96 floats (pad to 256)
    float* srcT = ws + 256;                           // N*B*HW*32 = 5,242,880
    float* refT = srcT + (size_t)NN * BB * HW * 32;   // B*HW*32 = 1,310,720

    prep_transpose<<<dim3(HW / 32, 10), 256, 0, stream>>>(src, ref, proj,
                                                          srcT, refT, mats);
    main_kernel<<<BB * HW, 256, 0, stream>>>(srcT, refT, depth, mats,
                                             regw, regb, out);
}

// Round 13
// 183.404 us; speedup vs baseline: 1.1274x; 1.0051x over previous
//
#include <hip/hip_runtime.h>
#include <hip/hip_bf16.h>
#include <math.h>

// Problem constants (from reference setup_inputs)
#define BB 2
#define CC 32
#define HH 128
#define WW 160
#define DD 32
#define NN 4
#define HW (HH * WW)        // 20480
#define GG 8

typedef float v2f __attribute__((ext_vector_type(2)));

// ---------------------------------------------------------------------------
// Device helper: per-(b,src) projection matrices (FP64 Gauss-Jordan).
// Executed by threads 0..7 of one block of the prep kernel.
// ---------------------------------------------------------------------------
__device__ void compute_mats(int t, const float* __restrict__ proj,
                             float* __restrict__ mats) {
    int b = t >> 2, n = t & 3;
    const float* Er = proj + ((size_t)(b * (NN + 1) + 0) * 2 + 0) * 16;
    const float* Kr = proj + ((size_t)(b * (NN + 1) + 0) * 2 + 1) * 16;
    const float* Es = proj + ((size_t)(b * (NN + 1) + n + 1) * 2 + 0) * 16;
    const float* Ks = proj + ((size_t)(b * (NN + 1) + n + 1) * 2 + 1) * 16;

    double A[4][4], Bm[4][4];
    for (int r = 0; r < 4; r++)
        for (int c = 0; c < 4; c++) {
            if (r < 3) {
                A[r][c]  = (double)Kr[r*4+0]*Er[0*4+c] + (double)Kr[r*4+1]*Er[1*4+c] + (double)Kr[r*4+2]*Er[2*4+c];
                Bm[r][c] = (double)Ks[r*4+0]*Es[0*4+c] + (double)Ks[r*4+1]*Es[1*4+c] + (double)Ks[r*4+2]*Es[2*4+c];
            } else {
                A[r][c]  = (double)Er[12 + c];
                Bm[r][c] = (double)Es[12 + c];
            }
        }
    double M[4][8];
    for (int i = 0; i < 4; i++)
        for (int j = 0; j < 4; j++) { M[i][j] = A[i][j]; M[i][4+j] = (i == j) ? 1.0 : 0.0; }
    for (int col = 0; col < 4; col++) {
        int piv = col;
        for (int r = col + 1; r < 4; r++)
            if (fabs(M[r][col]) > fabs(M[piv][col])) piv = r;
        if (piv != col)
            for (int j = 0; j < 8; j++) { double tmp = M[col][j]; M[col][j] = M[piv][j]; M[piv][j] = tmp; }
        double pv = M[col][col];
        for (int j = 0; j < 8; j++) M[col][j] /= pv;
        for (int r = 0; r < 4; r++) {
            if (r == col) continue;
            double f = M[r][col];
            for (int j = 0; j < 8; j++) M[r][j] -= f * M[col][j];
        }
    }
    float* o = mats + t * 12;
    for (int i = 0; i < 3; i++) {
        double p0 = 0, p1 = 0, p2 = 0, p3 = 0;
        for (int k = 0; k < 4; k++) {
            p0 += Bm[i][k] * M[k][4+0];
            p1 += Bm[i][k] * M[k][4+1];
            p2 += Bm[i][k] * M[k][4+2];
            p3 += Bm[i][k] * M[k][4+3];
        }
        o[i*3+0] = (float)p0; o[i*3+1] = (float)p1; o[i*3+2] = (float)p2;
        o[9 + i] = (float)p3;
    }
}

// ---------------------------------------------------------------------------
// Kernel 1: merged transpose [32][HW] -> [HW][32]; slabs 0-7 = src, 8-9 = ref.
// Vectorized: ONE float4 global read + ONE float4 global write per thread.
// Block (0,0) additionally computes the 8 projection matrices (tid<8).
// ---------------------------------------------------------------------------
__global__ __launch_bounds__(256) void prep_transpose(const float* __restrict__ src,
                                                      const float* __restrict__ ref,
                                                      const float* __restrict__ proj,
                                                      float* __restrict__ srcT,
                                                      float* __restrict__ refT,
                                                      float* __restrict__ mats) {
    if (blockIdx.x == 0 && blockIdx.y == 0 && threadIdx.x < 8)
        compute_mats(threadIdx.x, proj, mats);

    __shared__ float t[32][33];
    int slab = blockIdx.y;
    const float* ip;
    float* op;
    if (slab < 8) { ip = src + (size_t)slab * 32 * HW; op = srcT + (size_t)slab * 32 * HW; }
    else          { ip = ref + (size_t)(slab - 8) * 32 * HW; op = refT + (size_t)(slab - 8) * 32 * HW; }
    int hw0 = blockIdx.x * 32;
    int tt = threadIdx.x;
    int c  = tt >> 3;            // 0..31 (channel)
    int q  = tt & 7;             // 0..7  (quad within 32)

    float4 rv = *(const float4*)(ip + (size_t)c * HW + hw0 + 4 * q);
    t[c][4 * q + 0] = rv.x;
    t[c][4 * q + 1] = rv.y;
    t[c][4 * q + 2] = rv.z;
    t[c][4 * q + 3] = rv.w;
    __syncthreads();

    int hl = tt >> 3;            // 0..31 (hw within tile)
    float4 wv;
    wv.x = t[4 * q + 0][hl];
    wv.y = t[4 * q + 1][hl];
    wv.z = t[4 * q + 2][hl];
    wv.w = t[4 * q + 3][hl];
    *(float4*)(op + (size_t)(hw0 + hl) * 32 + 4 * q) = wv;
}

// ---------------------------------------------------------------------------
// Kernel 2: main fused kernel. Block = 256 threads = one ref pixel.
// Thread (d,g): d = tid>>3 (depth 0..31), g = tid&7 (channel group).
// XCD swizzle: p = (bid&7)*640 + (bid>>3).
// Phase 1 batches sources in PAIRS: 8 gathers in flight before first consume
// (halves exposed load latency; temps kept < 64 VGPR to hold wave capacity).
// ---------------------------------------------------------------------------
__global__ __launch_bounds__(256) void main_kernel(
    const float* __restrict__ srcT,   // (N*B, HW, 32) channels-last
    const float* __restrict__ refT,   // (B,   HW, 32) channels-last
    const float* __restrict__ depth,  // (B, D, H, W) original layout
    const float* __restrict__ mats,   // (B*N, 12) rot row-major + trans
    const float* __restrict__ regw,   // (8,)
    const float* __restrict__ regb,   // (1,)
    float* __restrict__ out)          // [B*HW depth][B*D*HW attn]
{
    int tid = threadIdx.x;
    int g  = tid & 7;
    int d  = tid >> 3;      // 0..31

    int bid = blockIdx.x;
    int p   = (bid & 7) * ((BB * HW) / 8) + (bid >> 3);  // XCD-contiguous band
    int b   = p / HW;
    int rem = p - b * HW;
    int y   = rem / WW;
    int x   = rem - y * WW;

    // this thread's group of the ref feature (one float4)
    float4 R = *(const float4*)(refT + (size_t)p * 32 + g * 4);
    v2f Rlo = { R.x, R.y }, Rhi = { R.z, R.w };
    float rwg = regw[g];
    float rb  = regb[0];

    __shared__ float4 sW[NN][DD + 1];  // bilinear weights per (n,d), padded
    __shared__ int4   sI[NN][DD + 1];  // pre-scaled (*8) tap indices, padded
    __shared__ float  sL[NN][DD + 8];  // per-source logits over depth, padded
    __shared__ float4 sCWT[DD];        // per-depth cw[4 sources] * 0.25
    __shared__ float  sCWS[DD];        // sum over sources of cw + 1e-8
    __shared__ float  sE[DD];          // final logits over depth
    __shared__ float  sDep[DD];        // depth hypothesis per d

    // ---- Phase 0 (waves 0-1 only): one thread per (n0, dd) homography
    if (tid < 128) {
        int n0 = tid & 3;
        int dd = tid >> 2;            // 0..31
        float fx = (float)x, fy = (float)y;
        float depM = depth[((size_t)(b * DD + dd) * HH + y) * WW + x];
        const float* Mp = mats + (size_t)(b * NN + n0) * 12;
        float4 m0 = *(const float4*)(Mp);       // rows are 48B -> 16B aligned
        float4 m1 = *(const float4*)(Mp + 4);
        float4 m2 = *(const float4*)(Mp + 8);
        float ax = m0.x * fx + m0.y * fy + m0.z;
        float ay = m0.w * fx + m1.x * fy + m1.y;
        float az = m1.z * fx + m1.w * fy + m2.x;
        float px = ax * depM + m2.y;
        float py = ay * depM + m2.z;
        float pz = az * depM + m2.w;
        float z  = (pz == 0.f) ? 1e-9f : pz;
        float rz = __builtin_amdgcn_rcpf(z);
        float gx = px * rz, gy = py * rz;

        float x0f = floorf(gx), y0f = floorf(gy);
        float wx = gx - x0f, wy = gy - y0f;
        bool vx0 = (x0f >= 0.f)  && (x0f <= (float)(WW - 1));
        bool vx1 = (x0f >= -1.f) && (x0f <= (float)(WW - 2));
        bool vy0 = (y0f >= 0.f)  && (y0f <= (float)(HH - 1));
        bool vy1 = (y0f >= -1.f) && (y0f <= (float)(HH - 2));
        float W00 = (vx0 && vy0) ? (1.f - wx) * (1.f - wy) : 0.f;
        float W10 = (vx1 && vy0) ? wx * (1.f - wy)         : 0.f;
        float W01 = (vx0 && vy1) ? (1.f - wx) * wy         : 0.f;
        float W11 = (vx1 && vy1) ? wx * wy                 : 0.f;

        int xi0 = (int)fminf(fmaxf(x0f,       0.f), (float)(WW - 1));
        int xi1 = (int)fminf(fmaxf(x0f + 1.f, 0.f), (float)(WW - 1));
        int yi0 = (int)fminf(fmaxf(y0f,       0.f), (float)(HH - 1));
        int yi1 = (int)fminf(fmaxf(y0f + 1.f, 0.f), (float)(HH - 1));

        sW[n0][dd] = make_float4(W00, W10, W01, W11);
        sI[n0][dd] = make_int4((yi0 * WW + xi0) * 8, (yi0 * WW + xi1) * 8,
                               (yi1 * WW + xi0) * 8, (yi1 * WW + xi1) * 8);
        if (n0 == 0) sDep[dd] = depM;
    }
    __syncthreads();   // barrier 0: sW/sI/sDep populated

    float cor[NN];

    // ---- Phase 1: pairwise-batched gathers + packed blend/dot + g-sum
#pragma unroll
    for (int np = 0; np < 2; np++) {
        int na = 2 * np, nb2 = 2 * np + 1;
        float4 wv0 = sW[na][d];
        int4   iv0 = sI[na][d];
        float4 wv1 = sW[nb2][d];
        int4   iv1 = sI[nb2][d];

        const float4* S0 = (const float4*)(srcT + (size_t)(na  * BB + b) * (32 * HW)) + g;
        const float4* S1 = (const float4*)(srcT + (size_t)(nb2 * BB + b) * (32 * HW)) + g;
        // batch both sources' 8 gathers before any consume
        float4 a0 = S0[iv0.x];
        float4 b0 = S0[iv0.y];
        float4 c0 = S0[iv0.z];
        float4 e0 = S0[iv0.w];
        float4 a1 = S1[iv1.x];
        float4 b1 = S1[iv1.y];
        float4 c1 = S1[iv1.z];
        float4 e1 = S1[iv1.w];

        // consume source na
        {
            v2f alo = { a0.x, a0.y }, ahi = { a0.z, a0.w };
            v2f blo = { b0.x, b0.y }, bhi = { b0.z, b0.w };
            v2f clo = { c0.x, c0.y }, chi = { c0.z, c0.w };
            v2f elo = { e0.x, e0.y }, ehi = { e0.z, e0.w };
            v2f wlo = wv0.x * alo + wv0.y * blo + wv0.z * clo + wv0.w * elo;
            v2f whi = wv0.x * ahi + wv0.y * bhi + wv0.z * chi + wv0.w * ehi;
            v2f pr  = wlo * Rlo + whi * Rhi;
            float cr = pr.x + pr.y;
            cor[na] = cr;
            float ls = cr;
            ls += __shfl_xor(ls, 1);
            ls += __shfl_xor(ls, 2);
            ls += __shfl_xor(ls, 4);
            if (g == 0) sL[na][d] = ls * 0.125f;
        }
        // consume source nb2
        {
            v2f alo = { a1.x, a1.y }, ahi = { a1.z, a1.w };
            v2f blo = { b1.x, b1.y }, bhi = { b1.z, b1.w };
            v2f clo = { c1.x, c1.y }, chi = { c1.z, c1.w };
            v2f elo = { e1.x, e1.y }, ehi = { e1.z, e1.w };
            v2f wlo = wv1.x * alo + wv1.y * blo + wv1.z * clo + wv1.w * elo;
            v2f whi = wv1.x * ahi + wv1.y * bhi + wv1.z * chi + wv1.w * ehi;
            v2f pr  = wlo * Rlo + whi * Rhi;
            float cr = pr.x + pr.y;
            cor[nb2] = cr;
            float ls = cr;
            ls += __shfl_xor(ls, 1);
            ls += __shfl_xor(ls, 2);
            ls += __shfl_xor(ls, 4);
            if (g == 0) sL[nb2][d] = ls * 0.125f;
        }
    }
    __syncthreads();   // barrier 1: sL fully populated

    // ---- Stats: wave 0 computes cw tables for all n,d
    if (tid < 64) {
        int n  = tid >> 4;       // 0..3
        int dh = tid & 15;       // 0..15; covers d=dh and d=dh+16
        float l0 = sL[n][dh];
        float l1 = sL[n][dh + 16];
        float m = fmaxf(l0, l1);
        m = fmaxf(m, __shfl_xor(m, 1));
        m = fmaxf(m, __shfl_xor(m, 2));
        m = fmaxf(m, __shfl_xor(m, 4));
        m = fmaxf(m, __shfl_xor(m, 8));
        float e0 = __expf(l0 - m), e1 = __expf(l1 - m);
        float s = e0 + e1;
        s += __shfl_xor(s, 1);
        s += __shfl_xor(s, 2);
        s += __shfl_xor(s, 4);
        s += __shfl_xor(s, 8);
        float f = 0.17677669529663687f / s;   // fold 1/sqrt(C=32)
        float c0 = e0 * f, c1 = e1 * f;
        // transposed, 0.25 (mean over C//G=4) pre-folded for phase 2's b128 read
        ((float*)&sCWT[dh])[n]      = c0 * 0.25f;
        ((float*)&sCWT[dh + 16])[n] = c1 * 0.25f;
        // cross-source sum per depth (lanes with same dh across the 4 n-groups)
        float t0 = c0, t1 = c1;
        t0 += __shfl_xor(t0, 16); t0 += __shfl_xor(t0, 32);
        t1 += __shfl_xor(t1, 16); t1 += __shfl_xor(t1, 32);
        if (n == 0) {
            sCWS[dh]      = t0 + 1e-8f;
            sCWS[dh + 16] = t1 + 1e-8f;
        }
    }
    __syncthreads();   // barrier 2: sCWT/sCWS ready

    // ---- Phase 2: per-thread weighted accumulation + reg projection
    float4 cwv = sCWT[d];
    float cf = cwv.x * cor[0] + cwv.y * cor[1] + cwv.z * cor[2] + cwv.w * cor[3];
    float v = cf * rwg;
    v += __shfl_xor(v, 1);
    v += __shfl_xor(v, 2);
    v += __shfl_xor(v, 4);
    float logit2 = v * __builtin_amdgcn_rcpf(sCWS[d]) + rb;  // same across octet
    if (g == 0) sE[d] = logit2;
    __syncthreads();   // barrier 3: sE fully populated

    // ---- Final: wave 0 alone — softmax over D, attn writes, argmax depth
    if (tid < 64) {
        int dl = tid & 31;               // both wave halves compute identically
        float q = sE[dl];
        float m2 = q;
        m2 = fmaxf(m2, __shfl_xor(m2, 1));
        m2 = fmaxf(m2, __shfl_xor(m2, 2));
        m2 = fmaxf(m2, __shfl_xor(m2, 4));
        m2 = fmaxf(m2, __shfl_xor(m2, 8));
        m2 = fmaxf(m2, __shfl_xor(m2, 16));
        float e2 = __expf(q - m2);
        float t2 = e2;
        t2 += __shfl_xor(t2, 1);
        t2 += __shfl_xor(t2, 2);
        t2 += __shfl_xor(t2, 4);
        t2 += __shfl_xor(t2, 8);
        t2 += __shfl_xor(t2, 16);
        float aw = e2 / t2;
        if (tid < 32)
            out[(size_t)BB * HW + (size_t)(b * DD + dl) * HW + rem] = aw;

        // argmax over D (first-max semantics), within each 32-lane half
        float bv = q; int bi = dl;
#pragma unroll
        for (int s = 1; s <= 16; s <<= 1) {
            float ov = __shfl_xor(bv, s);
            int   oi = __shfl_xor(bi, s);
            if (ov > bv || (ov == bv && oi < bi)) { bv = ov; bi = oi; }
        }
        if (tid < 32 && dl == bi) out[p] = sDep[bi];
    }
}

// ---------------------------------------------------------------------------
extern "C" void kernel_launch(void* const* d_in, const int* in_sizes, int n_in,
                              void* d_out, int out_size, void* d_ws, size_t ws_size,
                              hipStream_t stream) {
    const float* ref   = (const float*)d_in[0];  // (B,C,H,W)
    const float* src   = (const float*)d_in[1];  // (N,B,C,H,W)
    const float* proj  = (const float*)d_in[2];  // (B,N+1,2,4,4)
    const float* depth = (const float*)d_in[3];  // (B,D,H,W)
    const float* regw  = (const float*)d_in[4];  // (8,)
    const float* regb  = (const float*)d_in[5];  // (1,)
    float* out = (float*)d_out;

    float* ws   = (float*)d_ws;
    float* mats = ws;                                 // 96 floats (pad to 256)
    float* srcT = ws + 256;                           // N*B*HW*32 = 5,242,880
    float* refT = srcT + (size_t)NN * BB * HW * 32;   // B*HW*32 = 1,310,720

    prep_transpose<<<dim3(HW / 32, 10), 256, 0, stream>>>(src, ref, proj,
                                                          srcT, refT, mats);
    main_kernel<<<BB * HW, 256, 0, stream>>>(srcT, refT, depth, mats,
                                             regw, regb, out);
}